// Round 13
// baseline (839.394 us; speedup 1.0000x reference)
//
#include <hip/hip_runtime.h>
#include <math.h>

// Problem constants
#define NN 50000
#define NE 800000
#define MBLK 391           // (NN+127)/128 row blocks
#define ROWQ 48            // MBLK/8
#define ROWR 7             // MBLK%8

typedef __attribute__((ext_vector_type(8))) short  short8;   // 8 bf16 (4 VGPRs)
typedef __attribute__((ext_vector_type(4))) short  short4v;  // 4 bf16
typedef __attribute__((ext_vector_type(4))) float  floatx4;  // MFMA acc
typedef signed char schar8 __attribute__((ext_vector_type(8)));  // 8 int8

// bf16 bits <-> float helpers
__device__ __forceinline__ float bf2f(unsigned short u) {
    union { unsigned int i; float f; } v; v.i = ((unsigned int)u) << 16; return v.f;
}
__device__ __forceinline__ unsigned short f2bf(float f) {
    union { float f; unsigned int i; } v; v.f = f;
    unsigned int i = v.i;
    i += 0x7FFFu + ((i >> 16) & 1u);   // round to nearest even
    return (unsigned short)(i >> 16);
}

__device__ __forceinline__ float leaky(float v) { return (v > 0.f) ? v : 0.2f * v; }

// async 16B global -> LDS (gfx950 global_load_lds_dwordx4)
__device__ __forceinline__ void gload_lds16(const unsigned short* g, unsigned short* l) {
    __builtin_amdgcn_global_load_lds(
        (const __attribute__((address_space(1))) unsigned int*)g,
        (__attribute__((address_space(3))) unsigned int*)l, 16, 0, 0);
}

// ---------------------------------------------------------------------------
// CSR build
// ---------------------------------------------------------------------------
__global__ void deg_kernel(const int* __restrict__ edges, int* __restrict__ deg, int E) {
    int e = blockIdx.x * blockDim.x + threadIdx.x;
    if (e < E) atomicAdd(&deg[edges[2 * e + 1]], 1);
}

__global__ void scan_kernel(const int* __restrict__ deg, int* __restrict__ row_ptr,
                            int* __restrict__ cursor, int n) {
    __shared__ int sums[256];
    int t = threadIdx.x;
    const int C = (n + 255) / 256;
    int lo = t * C, hi = min(lo + C, n);
    if (lo > n) lo = n;
    if (hi < lo) hi = lo;
    int s = 0;
    for (int i = lo; i < hi; ++i) s += deg[i];
    sums[t] = s;
    __syncthreads();
    for (int off = 1; off < 256; off <<= 1) {
        int v = (t >= off) ? sums[t - off] : 0;
        __syncthreads();
        sums[t] += v;
        __syncthreads();
    }
    int run = (t == 0) ? 0 : sums[t - 1];
    for (int i = lo; i < hi; ++i) {
        int d = deg[i];
        row_ptr[i] = run;
        cursor[i]  = run;
        run += d;
    }
    if (t == 255) row_ptr[n] = sums[255];
}

__global__ void scatter_kernel(const int* __restrict__ edges, int* __restrict__ cursor,
                               int* __restrict__ edge_src, int* __restrict__ edge_dst, int E) {
    int e = blockIdx.x * blockDim.x + threadIdx.x;
    if (e < E) {
        int sv = edges[2 * e], d = edges[2 * e + 1];
        int pos = atomicAdd(&cursor[d], 1);
        if (pos >= 0 && pos < E) { edge_src[pos] = sv; edge_dst[pos] = d; }
    }
}

// ---------------------------------------------------------------------------
// Per-edge softmax weight precompute (layer 1 only): pw[e*4+h] = exp(leaky(.))
// ---------------------------------------------------------------------------
template <int H>
__global__ __launch_bounds__(256) void pw_kernel(const float* __restrict__ e_s,
                                                 const float* __restrict__ e_d,
                                                 const int* __restrict__ esrc,
                                                 const int* __restrict__ edst,
                                                 float* __restrict__ pw, int E) {
    int e = blockIdx.x * blockDim.x + threadIdx.x;
    if (e >= E) return;
    int s = esrc[e], d = edst[e];
    const float* ps = e_s + (size_t)s * H;
    const float* pd = e_d + (size_t)d * H;
#pragma unroll
    for (int h = 0; h < H; ++h)
        pw[(size_t)e * H + h] = __expf(leaky(ps[h] + pd[h]));
}

// ---------------------------------------------------------------------------
// prep2 mega-kernel (block-range partitioned, sections independent):
//   blocks [0,3336)      : weight prep (see offsets inline)
//   blocks [3336,3532)   : deg[NN] = 0
//   blocks [3532,9782)   : x0 fp32 -> x0b bf16
// NOTE: 768 is NOT a power of two — never use &767 (r7 bug).
// ---------------------------------------------------------------------------
__global__ __launch_bounds__(256) void prep2(
    const float* __restrict__ W1, const float* __restrict__ R1,
    const float* __restrict__ W2, const float* __restrict__ W3,
    const float* __restrict__ R3, const float* __restrict__ a1s,
    const float* __restrict__ a1d, const float* __restrict__ a3s,
    const float* __restrict__ a3d, const float* __restrict__ x0,
    unsigned short* __restrict__ w1t, unsigned short* __restrict__ r1t,
    unsigned short* __restrict__ w2t, unsigned short* __restrict__ w3t,
    unsigned short* __restrict__ r3t, float* __restrict__ wsb,
    float* __restrict__ wdb, float* __restrict__ a3sp, float* __restrict__ a3dp,
    int* __restrict__ deg, unsigned short* __restrict__ x0b) {
    const int b = blockIdx.x, t = threadIdx.x;

    if (b >= 3532) {                         // x0 conversion
        int i = ((b - 3532) * 256 + t) * 4;
        if (i + 3 < NN * 128) {
            float4 v = *(const float4*)(x0 + i);
            ushort4 o;
            o.x = f2bf(v.x); o.y = f2bf(v.y); o.z = f2bf(v.z); o.w = f2bf(v.w);
            *(ushort4*)(x0b + i) = o;
        }
        return;
    }
    if (b >= 3336) {                         // deg zero
        int i = (b - 3336) * 256 + t;
        if (i < NN) deg[i] = 0;
        return;
    }

    int idx = b * 256 + t;
    if (idx < 65536) {                       // w1t
        int n = idx >> 7, k = idx & 127;
        w1t[idx] = f2bf(W1[k * 512 + n]);
        return;
    }
    idx -= 65536;
    if (idx < 65536) {                       // r1t
        int n = idx >> 7, k = idx & 127;
        r1t[idx] = f2bf(R1[k * 512 + n]);
        return;
    }
    idx -= 65536;
    if (idx < 262144) {                      // w2t
        int n = idx >> 9, k = idx & 511;
        w2t[idx] = f2bf(W2[(size_t)k * 512 + n]);
        return;
    }
    idx -= 262144;
    if (idx < 393216) {                      // w3t head-padded
        int np = idx >> 9, k = idx & 511;
        int h = np >> 7, u = np & 127;
        w3t[idx] = f2bf((u < 121) ? W3[(size_t)k * 726 + h * 121 + u] : 0.f);
        return;
    }
    idx -= 393216;
    if (idx < 65536) {                       // r3t
        int n = idx >> 9, k = idx & 511;
        r3t[idx] = f2bf((n < 121) ? R3[(size_t)k * 121 + n] : 0.f);
        return;
    }
    idx -= 65536;
    if (idx < 512) {                         // combine_a (layer 1)
        int h = idx >> 7, k = idx & 127;
        float s = 0.f, d = 0.f;
        for (int u = 0; u < 128; ++u) {
            float w = W1[k * 512 + h * 128 + u];
            s = fmaf(w, a1s[h * 128 + u], s);
            d = fmaf(w, a1d[h * 128 + u], d);
        }
        wsb[idx] = s;
        wdb[idx] = d;
        return;
    }
    idx -= 512;
    if (idx < 1536) {                        // a3 padding (explicit arithmetic)
        int which = (idx >= 768) ? 1 : 0;
        int j = idx - which * 768;           // j in [0,768)
        int h = j >> 7, u = j & 127;
        float val = (u < 121) ? (which ? a3d[h * 121 + u] : a3s[h * 121 + u]) : 0.f;
        if (which) a3dp[j] = val; else a3sp[j] = val;
    }
}

// ---------------------------------------------------------------------------
// GEMM + fused escore + int8 quant. 1-D grid, XCD-grouped remap (r11):
//   xcd = bid&7 owns contiguous row-blocks; NX head blocks of one row-block
//   launch back-to-back on one XCD -> A panel fetched once per XCD.
// LDS bank swizzle: chunk c' = c ^ ((row>>1)&3) on global source AND ds_read.
// Outputs: Cq int8 [M][NS]; esq float2 {e_s, scl}[M][Hl]; e_d[M][Hl].
// Head with col0==768 (layer 3): R3 residual -> fp32 resout[M][121].
// ---------------------------------------------------------------------------
__global__ __launch_bounds__(256) void gemm_esc(const unsigned short* __restrict__ A,
                                                const unsigned short* __restrict__ BT,
                                                signed char* __restrict__ Cq,
                                                float2* __restrict__ esq,
                                                float* __restrict__ e_d,
                                                const float* __restrict__ asv,
                                                const float* __restrict__ adv,
                                                float* __restrict__ resout,
                                                int M, int NS, int Hl, int NX) {
    __shared__ __align__(16) unsigned short As[128 * 32];
    __shared__ __align__(16) unsigned short Bs[128 * 32];

    // XCD-grouped block remap (bijective; MBLK=391 = 8*48+7)
    const int xcd = blockIdx.x & 7, pos = blockIdx.x >> 3;
    const int nrows = ROWQ + (xcd < ROWR ? 1 : 0);
    if (pos >= nrows * NX) return;
    const int ybase = xcd * ROWQ + min(xcd, ROWR);
    const int by = ybase + pos / NX;
    const int bx = pos - (pos / NX) * NX;

    const int t    = threadIdx.x;
    const int wave = t >> 6, lane = t & 63;
    const int wm   = (wave >> 1) * 64, wn = (wave & 1) * 64;
    const int l15  = lane & 15, q = lane >> 4;
    const int row0 = by * 128, col0 = bx * 128;

    floatx4 acc[4][4];
#pragma unroll
    for (int i = 0; i < 4; ++i)
#pragma unroll
        for (int j = 0; j < 4; ++j) acc[i][j] = (floatx4){0.f, 0.f, 0.f, 0.f};

    for (int k0 = 0; k0 < 512; k0 += 32) {
#pragma unroll
        for (int p = 0; p < 2; ++p) {
            int idx = p * 256 + t;
            int r = idx >> 2, qq = idx & 3;
            int cc = qq ^ ((r >> 1) & 3);     // bank-conflict swizzle (source side)
            int ar = row0 + r; ar = (ar < M) ? ar : (M - 1);
            unsigned short* ldsA = As + (p * 2048 + wave * 512);
            unsigned short* ldsB = Bs + (p * 2048 + wave * 512);
            gload_lds16(A  + (size_t)ar * 512 + k0 + cc * 8, ldsA);
            gload_lds16(BT + (size_t)(col0 + r) * 512 + k0 + cc * 8, ldsB);
        }
        __syncthreads();

        short8 af[4], bfr[4];
#pragma unroll
        for (int mi = 0; mi < 4; ++mi) {
            int row = wm + 16 * mi + l15;
            af[mi] = *(const short8*)&As[row * 32 + (q ^ ((row >> 1) & 3)) * 8];
        }
#pragma unroll
        for (int ni = 0; ni < 4; ++ni) {
            int row = wn + 16 * ni + l15;
            bfr[ni] = *(const short8*)&Bs[row * 32 + (q ^ ((row >> 1) & 3)) * 8];
        }
#pragma unroll
        for (int mi = 0; mi < 4; ++mi)
#pragma unroll
            for (int ni = 0; ni < 4; ++ni)
                acc[mi][ni] = __builtin_amdgcn_mfma_f32_16x16x32_bf16(af[mi], bfr[ni], acc[mi][ni], 0, 0, 0);
        __syncthreads();
    }

    if (col0 == 768) {
        // R3 residual head: fp32 store to resout[M][121], no escore/quant.
#pragma unroll
        for (int ni = 0; ni < 4; ++ni) {
            int gcl = wn + 16 * ni + l15;
            if (gcl >= 121) continue;
#pragma unroll
            for (int mi = 0; mi < 4; ++mi) {
#pragma unroll
                for (int r = 0; r < 4; ++r) {
                    int gr = row0 + wm + 16 * mi + q * 4 + r;
                    if (gr < M) resout[(size_t)gr * 121 + gcl] = acc[mi][ni][r];
                }
            }
        }
        return;
    }

    // shared reduction buffers (reuse As): sred[256] escore sums, sredm[128] rowmax
    float* sred  = (float*)As;
    int*   sredm = (int*)(sred + 256);
    if (t < 256) sred[t] = 0.f;
    if (t < 128) sredm[t] = 0;
    __syncthreads();

    float av[4], dv[4];
#pragma unroll
    for (int ni = 0; ni < 4; ++ni) {
        int gc = col0 + wn + 16 * ni + l15;
        av[ni] = asv[gc];
        dv[ni] = adv[gc];
    }
#pragma unroll
    for (int mi = 0; mi < 4; ++mi) {
#pragma unroll
        for (int r = 0; r < 4; ++r) {
            float ps = 0.f, pd = 0.f, mx = 0.f;
#pragma unroll
            for (int ni = 0; ni < 4; ++ni) {
                ps = fmaf(acc[mi][ni][r], av[ni], ps);
                pd = fmaf(acc[mi][ni][r], dv[ni], pd);
                mx = fmaxf(mx, fabsf(acc[mi][ni][r]));
            }
#pragma unroll
            for (int off = 1; off < 16; off <<= 1) {
                ps += __shfl_xor(ps, off);
                pd += __shfl_xor(pd, off);
                mx = fmaxf(mx, __shfl_xor(mx, off));
            }
            if (l15 == 0) {
                int rloc = wm + 16 * mi + 4 * q + r;
                atomicAdd(&sred[rloc * 2 + 0], ps);
                atomicAdd(&sred[rloc * 2 + 1], pd);
                atomicMax(&sredm[rloc], __float_as_int(mx));
            }
        }
    }
    __syncthreads();

    // int8 store
#pragma unroll
    for (int mi = 0; mi < 4; ++mi) {
#pragma unroll
        for (int r = 0; r < 4; ++r) {
            int rloc = wm + 16 * mi + 4 * q + r;
            float rm = fmaxf(__int_as_float(sredm[rloc]), 1e-20f);
            float iq = 127.f / rm;
            int gr = row0 + rloc;
#pragma unroll
            for (int ni = 0; ni < 4; ++ni) {
                int gc = col0 + wn + 16 * ni + l15;
                if (gr < M)
                    Cq[(size_t)gr * NS + gc] = (signed char)(int)rintf(acc[mi][ni][r] * iq);
            }
        }
    }

    if (t < 128) {
        int gr = row0 + t;
        if (gr < M) {
            float2 ev;
            ev.x = sred[t * 2 + 0];
            ev.y = fmaxf(__int_as_float(sredm[t]), 1e-20f) * (1.f / 127.f);
            esq[(size_t)gr * Hl + bx] = ev;
            e_d[(size_t)gr * Hl + bx] = sred[t * 2 + 1];
        }
    }
}

// ---------------------------------------------------------------------------
// Layer-1 fused GEMM: x1 = elu(aggx_h @ W1_h + x0 @ R1_h), blockIdx.x = head.
// ---------------------------------------------------------------------------
__global__ __launch_bounds__(256) void gemm_l1(const unsigned short* __restrict__ aggx,
                                               const unsigned short* __restrict__ w1t,
                                               const unsigned short* __restrict__ x0b,
                                               const unsigned short* __restrict__ r1t,
                                               unsigned short* __restrict__ C, int M) {
    __shared__ __align__(16) unsigned short As[128 * 32];
    __shared__ __align__(16) unsigned short Bs[128 * 32];

    const int t    = threadIdx.x;
    const int wave = t >> 6, lane = t & 63;
    const int wm   = (wave >> 1) * 64, wn = (wave & 1) * 64;
    const int l15  = lane & 15, q = lane >> 4;
    const int row0 = blockIdx.y * 128;
    const int head = blockIdx.x;
    const int ccol = head * 128;

    floatx4 acc[4][4];
#pragma unroll
    for (int i = 0; i < 4; ++i)
#pragma unroll
        for (int j = 0; j < 4; ++j) acc[i][j] = (floatx4){0.f, 0.f, 0.f, 0.f};

    for (int ph = 0; ph < 2; ++ph) {
        const unsigned short* A  = ph ? x0b : (aggx + ccol);
        const int AS             = ph ? 128 : 512;
        const unsigned short* BT = (ph ? r1t : w1t) + (size_t)ccol * 128;

        for (int k0 = 0; k0 < 128; k0 += 32) {
#pragma unroll
            for (int p = 0; p < 2; ++p) {
                int idx = p * 256 + t;
                int r = idx >> 2, qq = idx & 3;
                int ar = row0 + r; ar = (ar < M) ? ar : (M - 1);
                unsigned short* ldsA = As + (p * 2048 + wave * 512);
                unsigned short* ldsB = Bs + (p * 2048 + wave * 512);
                gload_lds16(A  + (size_t)ar * AS + k0 + qq * 8, ldsA);
                gload_lds16(BT + (size_t)r * 128 + k0 + qq * 8, ldsB);
            }
            __syncthreads();

            short8 af[4], bfr[4];
#pragma unroll
            for (int mi = 0; mi < 4; ++mi) af[mi]  = *(const short8*)&As[(wm + 16 * mi + l15) * 32 + q * 8];
#pragma unroll
            for (int ni = 0; ni < 4; ++ni) bfr[ni] = *(const short8*)&Bs[(wn + 16 * ni + l15) * 32 + q * 8];
#pragma unroll
            for (int mi = 0; mi < 4; ++mi)
#pragma unroll
                for (int ni = 0; ni < 4; ++ni)
                    acc[mi][ni] = __builtin_amdgcn_mfma_f32_16x16x32_bf16(af[mi], bfr[ni], acc[mi][ni], 0, 0, 0);
            __syncthreads();
        }
    }

#pragma unroll
    for (int ni = 0; ni < 4; ++ni) {
        int gc = ccol + wn + 16 * ni + l15;
#pragma unroll
        for (int mi = 0; mi < 4; ++mi) {
#pragma unroll
            for (int r = 0; r < 4; ++r) {
                int gr = row0 + wm + 16 * mi + q * 4 + r;
                if (gr < M) {
                    float z = acc[mi][ni][r];
                    z = (z > 0.f) ? z : (__expf(z) - 1.f);   // elu
                    C[(size_t)gr * 512 + gc] = f2bf(z);
                }
            }
        }
    }
}

// ---------------------------------------------------------------------------
// escore over x (layer 1): e_s[n,h] = x[n] . ws[h], 128-dim, 4 heads.
// ---------------------------------------------------------------------------
__global__ __launch_bounds__(256) void escore_x(const unsigned short* __restrict__ x,
                                                const float* __restrict__ ws,
                                                const float* __restrict__ wd,
                                                float* __restrict__ e_s,
                                                float* __restrict__ e_d) {
    const int wave = threadIdx.x >> 6, lane = threadIdx.x & 63;
    const int n = blockIdx.x * 4 + wave;
    const int h = lane >> 4, seg = lane & 15;

    short8 hv = *(const short8*)(x + (size_t)n * 128 + seg * 8);
    float4 w0 = *(const float4*)(ws + h * 128 + seg * 8);
    float4 w1 = *(const float4*)(ws + h * 128 + seg * 8 + 4);
    float4 d0 = *(const float4*)(wd + h * 128 + seg * 8);
    float4 d1 = *(const float4*)(wd + h * 128 + seg * 8 + 4);
    float av[8] = {w0.x, w0.y, w0.z, w0.w, w1.x, w1.y, w1.z, w1.w};
    float dv[8] = {d0.x, d0.y, d0.z, d0.w, d1.x, d1.y, d1.z, d1.w};

    float ps = 0.f, pd = 0.f;
#pragma unroll
    for (int j = 0; j < 8; ++j) {
        float xv = bf2f((unsigned short)hv[j]);
        ps = fmaf(xv, av[j], ps);
        pd = fmaf(xv, dv[j], pd);
    }
#pragma unroll
    for (int off = 1; off < 16; off <<= 1) {
        ps += __shfl_xor(ps, off);
        pd += __shfl_xor(pd, off);
    }
    if (seg == 0) {
        e_s[(size_t)n * 4 + h] = ps;
        e_d[(size_t)n * 4 + h] = pd;
    }
}

// ---------------------------------------------------------------------------
// Layer-1 x-aggregation: aggx[n,h,u] = (1/den_h) sum_e pw[e,h] x[src_e, u].
// ---------------------------------------------------------------------------
__global__ __launch_bounds__(256) void agg_x512(const unsigned short* __restrict__ x,
                                                const float* __restrict__ pw,
                                                const int* __restrict__ rowp,
                                                const int* __restrict__ esrc,
                                                unsigned short* __restrict__ aggx) {
    const int wave = threadIdx.x >> 6, lane = threadIdx.x & 63;
    const int n = blockIdx.x * 4 + wave;
    const int lid = lane & 31, half = lane >> 5;
    const int beg = rowp[n], end = rowp[n + 1];

    float den[4] = {0.f, 0.f, 0.f, 0.f};
    float acc[4][4];
#pragma unroll
    for (int h = 0; h < 4; ++h)
#pragma unroll
        for (int j = 0; j < 4; ++j) acc[h][j] = 0.f;

    int e = beg;
    for (; e + 8 <= end; e += 8) {
        int s[4];
        float4 p[4];
        short4v xr[4];
#pragma unroll
        for (int k = 0; k < 4; ++k) s[k] = esrc[e + 2 * k + half];
#pragma unroll
        for (int k = 0; k < 4; ++k) p[k] = *(const float4*)(pw + (size_t)(e + 2 * k + half) * 4);
#pragma unroll
        for (int k = 0; k < 4; ++k) xr[k] = *(const short4v*)(x + (size_t)s[k] * 128 + lid * 4);
#pragma unroll
        for (int k = 0; k < 4; ++k) {
            den[0] += p[k].x; den[1] += p[k].y; den[2] += p[k].z; den[3] += p[k].w;
#pragma unroll
            for (int j = 0; j < 4; ++j) {
                float xf = bf2f((unsigned short)xr[k][j]);
                acc[0][j] = fmaf(p[k].x, xf, acc[0][j]);
                acc[1][j] = fmaf(p[k].y, xf, acc[1][j]);
                acc[2][j] = fmaf(p[k].z, xf, acc[2][j]);
                acc[3][j] = fmaf(p[k].w, xf, acc[3][j]);
            }
        }
    }
    for (; e < end; e += 2) {
        int idx = e + half;
        if (idx < end) {
            int s = esrc[idx];
            float4 p = *(const float4*)(pw + (size_t)idx * 4);
            short4v xr = *(const short4v*)(x + (size_t)s * 128 + lid * 4);
            den[0] += p.x; den[1] += p.y; den[2] += p.z; den[3] += p.w;
#pragma unroll
            for (int j = 0; j < 4; ++j) {
                float xf = bf2f((unsigned short)xr[j]);
                acc[0][j] = fmaf(p.x, xf, acc[0][j]);
                acc[1][j] = fmaf(p.y, xf, acc[1][j]);
                acc[2][j] = fmaf(p.z, xf, acc[2][j]);
                acc[3][j] = fmaf(p.w, xf, acc[3][j]);
            }
        }
    }

    // combine half-waves
#pragma unroll
    for (int h = 0; h < 4; ++h) {
        den[h] += __shfl_xor(den[h], 32);
#pragma unroll
        for (int j = 0; j < 4; ++j) acc[h][j] += __shfl_xor(acc[h][j], 32);
    }
    if (half == 0) {
#pragma unroll
        for (int h = 0; h < 4; ++h) {
            const float inv = 1.f / fmaxf(den[h], 1e-9f);
            ushort4 o;
            o.x = f2bf(acc[h][0] * inv);
            o.y = f2bf(acc[h][1] * inv);
            o.z = f2bf(acc[h][2] * inv);
            o.w = f2bf(acc[h][3] * inv);
            *(ushort4*)(aggx + (size_t)n * 512 + h * 128 + lid * 4) = o;
        }
    }
}

// ---------------------------------------------------------------------------
// Wave-per-node aggregation, layer 2, int8 hbuf stride 512 + packed
// esq {e_s, scl} float2. den uses unscaled p; acc uses p*scl. 8-edge pipeline.
// ---------------------------------------------------------------------------
__global__ __launch_bounds__(256) void agg_q512(const signed char* __restrict__ hq,
                                                const float2* __restrict__ esq,
                                                const float* __restrict__ ed,
                                                const int* __restrict__ rowp,
                                                const int* __restrict__ esrc,
                                                const unsigned short* res,
                                                unsigned short* out) {
    const int wave = threadIdx.x >> 6, lane = threadIdx.x & 63;
    const int n = blockIdx.x * 4 + wave;      // grid*4 == NN exactly
    const int h = lane >> 4;
    const int beg = rowp[n], end = rowp[n + 1];
    const float edh = ed[(size_t)n * 4 + h];

    float den = 0.f;
    float acc[8];
#pragma unroll
    for (int j = 0; j < 8; ++j) acc[j] = 0.f;

    int e = beg;
    for (; e + 8 <= end; e += 8) {
        int s[8];
#pragma unroll
        for (int k = 0; k < 8; ++k) s[k] = esrc[e + k];
        schar8 r[8];
#pragma unroll
        for (int k = 0; k < 8; ++k) r[k] = *(const schar8*)(hq + (size_t)s[k] * 512 + lane * 8);
        float p[8], qv[8];
#pragma unroll
        for (int k = 0; k < 8; ++k) {
            float2 ev = esq[(size_t)s[k] * 4 + h];
            float pv = __expf(leaky(ev.x + edh));
            p[k] = pv;
            qv[k] = pv * ev.y;
        }
#pragma unroll
        for (int k = 0; k < 8; ++k) den += p[k];
#pragma unroll
        for (int j = 0; j < 8; ++j) {
            float a = acc[j];
#pragma unroll
            for (int k = 0; k < 8; ++k) a = fmaf(qv[k], (float)r[k][j], a);
            acc[j] = a;
        }
    }
    for (; e < end; ++e) {
        int s0 = esrc[e];
        schar8 r0 = *(const schar8*)(hq + (size_t)s0 * 512 + lane * 8);
        float2 ev = esq[(size_t)s0 * 4 + h];
        float p0 = __expf(leaky(ev.x + edh));
        float q0 = p0 * ev.y;
        den += p0;
#pragma unroll
        for (int j = 0; j < 8; ++j) acc[j] = fmaf(q0, (float)r0[j], acc[j]);
    }

    const float inv = 1.f / fmaxf(den, 1e-9f);
    short8 rv = *(const short8*)(res + (size_t)n * 512 + lane * 8);
    short8 ov;
#pragma unroll
    for (int j = 0; j < 8; ++j) {
        float z = acc[j] * inv + bf2f((unsigned short)rv[j]);
        z = (z > 0.f) ? z : (__expf(z) - 1.f);   // elu
        ov[j] = (short)f2bf(z);
    }
    *(short8*)(out + (size_t)n * 512 + lane * 8) = ov;
}

// ---------------------------------------------------------------------------
// Wave-per-node aggregation, layer 3, int8 stride 768, packed esq.
// Chunk0 (heads 0-3): all 64 lanes, 4 edges/group. Chunk1 (heads 4,5):
// BALANCED — each wave half processes 2 of the 4 edges for elements
// 512 + (lane&31)*8; acc1/den1 reduced via shfl_xor(32) at the end
// (r12: was exec-masked on lanes<32 = 33% wasted VALU slots).
// ---------------------------------------------------------------------------
__global__ __launch_bounds__(256) void agg_q768(const signed char* __restrict__ hq,
                                                const float2* __restrict__ esq,
                                                const float* __restrict__ ed,
                                                const int* __restrict__ rowp,
                                                const int* __restrict__ esrc,
                                                const float* res,
                                                float* out) {
    __shared__ float s_vals[4][768];
    const int wave = threadIdx.x >> 6, lane = threadIdx.x & 63;
    const int n = blockIdx.x * 4 + wave;
    const int beg = rowp[n], end = rowp[n + 1];

    const int h0 = lane >> 4;                  // chunk0 head (0..3)
    const int l31 = lane & 31, half = lane >> 5;
    const int h1 = 4 + (l31 >> 4);             // chunk1 head (4,5)
    const float edh0 = ed[(size_t)n * 6 + h0];
    const float edh1 = ed[(size_t)n * 6 + h1];

    float den0 = 0.f, den1 = 0.f;
    float acc0[8], acc1[8];
#pragma unroll
    for (int j = 0; j < 8; ++j) { acc0[j] = 0.f; acc1[j] = 0.f; }

    int e = beg;
    for (; e + 4 <= end; e += 4) {
        int s[4];
#pragma unroll
        for (int k = 0; k < 4; ++k) s[k] = esrc[e + k];
        // chunk0: all lanes, all 4 edges
        schar8 r0[4];
#pragma unroll
        for (int k = 0; k < 4; ++k) r0[k] = *(const schar8*)(hq + (size_t)s[k] * 768 + lane * 8);
        float p0[4], q0[4];
#pragma unroll
        for (int k = 0; k < 4; ++k) {
            float2 ev = esq[(size_t)s[k] * 6 + h0];
            float pv = __expf(leaky(ev.x + edh0));
            p0[k] = pv;
            q0[k] = pv * ev.y;
        }
        den0 += (p0[0] + p0[1]) + (p0[2] + p0[3]);
#pragma unroll
        for (int j = 0; j < 8; ++j)
            acc0[j] = fmaf(q0[0], (float)r0[0][j],
                      fmaf(q0[1], (float)r0[1][j],
                      fmaf(q0[2], (float)r0[2][j],
                      fmaf(q0[3], (float)r0[3][j], acc0[j]))));
        // chunk1: this half's 2 edges
        int sA = s[half * 2], sB = s[half * 2 + 1];
        schar8 rA = *(const schar8*)(hq + (size_t)sA * 768 + 512 + l31 * 8);
        schar8 rB = *(const schar8*)(hq + (size_t)sB * 768 + 512 + l31 * 8);
        float2 evA = esq[(size_t)sA * 6 + h1];
        float2 evB = esq[(size_t)sB * 6 + h1];
        float pA = __expf(leaky(evA.x + edh1));
        float pB = __expf(leaky(evB.x + edh1));
        float qA = pA * evA.y, qB = pB * evB.y;
        den1 += pA + pB;
#pragma unroll
        for (int j = 0; j < 8; ++j)
            acc1[j] = fmaf(qA, (float)rA[j], fmaf(qB, (float)rB[j], acc1[j]));
    }
    for (; e < end; ++e) {
        int s = esrc[e];
        schar8 r0 = *(const schar8*)(hq + (size_t)s * 768 + lane * 8);
        float2 ev0 = esq[(size_t)s * 6 + h0];
        float p0 = __expf(leaky(ev0.x + edh0));
        float q0 = p0 * ev0.y;
        den0 += p0;
#pragma unroll
        for (int j = 0; j < 8; ++j) acc0[j] = fmaf(q0, (float)r0[j], acc0[j]);
        if (half == 0) {                       // tail chunk1: half 0 only
            schar8 r1 = *(const schar8*)(hq + (size_t)s * 768 + 512 + l31 * 8);
            float2 ev1 = esq[(size_t)s * 6 + h1];
            float p1 = __expf(leaky(ev1.x + edh1));
            float q1 = p1 * ev1.y;
            den1 += p1;
#pragma unroll
            for (int j = 0; j < 8; ++j) acc1[j] = fmaf(q1, (float)r1[j], acc1[j]);
        }
    }

    // reduce chunk1 across halves
    den1 += __shfl_xor(den1, 32);
#pragma unroll
    for (int j = 0; j < 8; ++j) acc1[j] += __shfl_xor(acc1[j], 32);

    const float inv0 = 1.f / fmaxf(den0, 1e-9f);
#pragma unroll
    for (int j = 0; j < 8; ++j) s_vals[wave][lane * 8 + j] = acc0[j] * inv0;
    if (lane < 32) {
        const float inv1 = 1.f / fmaxf(den1, 1e-9f);
#pragma unroll
        for (int j = 0; j < 8; ++j) s_vals[wave][512 + l31 * 8 + j] = acc1[j] * inv1;
    }
    __syncthreads();

    for (int u = lane; u < 121; u += 64) {
        float sum = 0.f;
#pragma unroll
        for (int hh = 0; hh < 6; ++hh) sum += s_vals[wave][hh * 128 + u];
        float v = sum * (1.f / 6.f) + res[(size_t)n * 121 + u];
        __builtin_nontemporal_store(v, out + (size_t)n * 121 + u);
    }
}

// ---------------------------------------------------------------------------
// Launch
// ---------------------------------------------------------------------------
static inline size_t align256(size_t x) { return (x + 255) & ~(size_t)255; }

extern "C" void kernel_launch(void* const* d_in, const int* in_sizes, int n_in,
                              void* d_out, int out_size, void* d_ws, size_t ws_size,
                              hipStream_t stream) {
    const float* x0  = (const float*)d_in[0];   // [50000,128] fp32
    const int* edges = (const int*)d_in[1];     // [800000,2] int32
    const float* W1  = (const float*)d_in[2];   // [128,512]
    const float* a1s = (const float*)d_in[3];
    const float* a1d = (const float*)d_in[4];
    const float* R1  = (const float*)d_in[5];   // [128,512]
    const float* W2  = (const float*)d_in[6];   // [512,512]
    const float* a2s = (const float*)d_in[7];
    const float* a2d = (const float*)d_in[8];
    const float* W3  = (const float*)d_in[9];   // [512,726]
    const float* a3s = (const float*)d_in[10];
    const float* a3d = (const float*)d_in[11];
    const float* R3  = (const float*)d_in[12];  // [512,121]
    float* out = (float*)d_out;                 // [50000,121] fp32

    // workspace carve (~160 MB). w3t/r3t MUST stay contiguous (gemm_esc R3 head).
    char* w = (char*)d_ws;
    size_t off = 0;
    unsigned short* hbuf = (unsigned short*)(w + off); off = align256(off + (size_t)NN * 768 * 2);
    unsigned short* x1   = (unsigned short*)(w + off); off = align256(off + (size_t)NN * 512 * 2);
    float* es  = (float*)(w + off); off = align256(off + (size_t)NN * 6 * 4);
    float* ed  = (float*)(w + off); off = align256(off + (size_t)NN * 6 * 4);
    int* rowp  = (int*)(w + off);   off = align256(off + (size_t)(NN + 1) * 4);
    int* esrc  = (int*)(w + off);   off = align256(off + (size_t)NE * 4);
    int* edst  = (int*)(w + off);   off = align256(off + (size_t)NE * 4);
    float* pw  = (float*)(w + off); off = align256(off + (size_t)NE * 4 * 4 + 256);
    unsigned short* w1t = (unsigned short*)(w + off); off = align256(off + (size_t)512 * 128 * 2);
    unsigned short* r1t = (unsigned short*)(w + off); off = align256(off + (size_t)512 * 128 * 2);
    unsigned short* w2t = (unsigned short*)(w + off); off = align256(off + (size_t)512 * 512 * 2);
    unsigned short* w3t = (unsigned short*)(w + off); off = align256(off + (size_t)768 * 512 * 2);
    unsigned short* r3t = (unsigned short*)(w + off); off = align256(off + (size_t)128 * 512 * 2);
    float* wsb = (float*)(w + off); off = align256(off + (size_t)512 * 4);
    float* wdb = (float*)(w + off); off = align256(off + (size_t)512 * 4);
    float* a3sp = (float*)(w + off); off = align256(off + (size_t)768 * 4);
    float* a3dp = (float*)(w + off); off = align256(off + (size_t)768 * 4);
    float2* esq = (float2*)(w + off); off = align256(off + (size_t)NN * 6 * 8);
    int* deg = (int*)es;                     // overlay: dead after CSR build
    int* cur = (int*)ed;
    // layer-1 overlays inside hbuf (hbuf not used until layer-2 GEMM writes it):
    unsigned short* x0b  = hbuf;                          // [NN,128] bf16 = 12.8 MB
    unsigned short* aggx = hbuf + (size_t)NN * 128;       // [NN,512] bf16 = 51.2 MB
    signed char* hq = (signed char*)hbuf;                 // int8 views (L2: 25.6 MB, L3: 38.4 MB)
    (void)ws_size;

    const int EB = (NE + 255) / 256;
    const int MB = MBLK;               // 391
    const int AB = NN / 4;             // 12500 blocks, 4 waves each

    // --- prep (weights + deg zero + x0 conversion, one dispatch) ---
    prep2<<<9782, 256, 0, stream>>>(W1, R1, W2, W3, R3, a1s, a1d, a3s, a3d, x0,
                                    w1t, r1t, w2t, w3t, r3t, wsb, wdb, a3sp, a3dp,
                                    deg, x0b);

    // --- CSR build ---
    deg_kernel<<<EB, 256, 0, stream>>>(edges, deg, NE);
    scan_kernel<<<1, 256, 0, stream>>>(deg, rowp, cur, NN);
    scatter_kernel<<<EB, 256, 0, stream>>>(edges, cur, esrc, edst, NE);

    // --- Layer 1 (x-aggregation + fused dual-K GEMM) ---
    escore_x<<<AB, 256, 0, stream>>>(x0b, wsb, wdb, es, ed);
    pw_kernel<4><<<EB, 256, 0, stream>>>(es, ed, esrc, edst, pw, NE);
    agg_x512<<<AB, 256, 0, stream>>>(x0b, pw, rowp, esrc, aggx);
    gemm_l1<<<dim3(4, MB), 256, 0, stream>>>(aggx, w1t, x0b, r1t, x1, NN);

    // --- Layer 2: GEMM + escore + int8 quant (XCD-grouped grid 8*49*4=1568) ---
    gemm_esc<<<8 * 49 * 4, 256, 0, stream>>>(x1, w2t, hq, esq, ed,
                                             a2s, a2d, out, NN, 512, 4, 4);
    agg_q512<<<AB, 256, 0, stream>>>(hq, esq, ed, rowp, esrc, x1, x1);

    // --- Layer 3: GEMM + escore + int8 quant + R3 head (grid 8*49*7=2744) ---
    gemm_esc<<<8 * 49 * 7, 256, 0, stream>>>(x1, w3t, hq, esq, ed,
                                             a3sp, a3dp, out, NN, 768, 6, 7);
    agg_q768<<<AB, 256, 0, stream>>>(hq, esq, ed, rowp, esrc, out, out);
}

// Round 14
// 799.899 us; speedup vs baseline: 1.0494x; 1.0494x over previous
//
#include <hip/hip_runtime.h>
#include <math.h>

// Problem constants
#define NN 50000
#define NE 800000
#define MBLK 391           // (NN+127)/128 row blocks
#define ROWQ 48            // MBLK/8
#define ROWR 7             // MBLK%8

typedef __attribute__((ext_vector_type(8))) short  short8;   // 8 bf16 (4 VGPRs)
typedef __attribute__((ext_vector_type(4))) short  short4v;  // 4 bf16
typedef __attribute__((ext_vector_type(4))) float  floatx4;  // MFMA acc
typedef signed char schar8 __attribute__((ext_vector_type(8)));  // 8 int8

// bf16 bits <-> float helpers
__device__ __forceinline__ float bf2f(unsigned short u) {
    union { unsigned int i; float f; } v; v.i = ((unsigned int)u) << 16; return v.f;
}
__device__ __forceinline__ unsigned short f2bf(float f) {
    union { float f; unsigned int i; } v; v.f = f;
    unsigned int i = v.i;
    i += 0x7FFFu + ((i >> 16) & 1u);   // round to nearest even
    return (unsigned short)(i >> 16);
}

__device__ __forceinline__ float leaky(float v) { return (v > 0.f) ? v : 0.2f * v; }

// async 16B global -> LDS (gfx950 global_load_lds_dwordx4)
__device__ __forceinline__ void gload_lds16(const unsigned short* g, unsigned short* l) {
    __builtin_amdgcn_global_load_lds(
        (const __attribute__((address_space(1))) unsigned int*)g,
        (__attribute__((address_space(3))) unsigned int*)l, 16, 0, 0);
}

// ---------------------------------------------------------------------------
// CSR build
// ---------------------------------------------------------------------------
__global__ void deg_kernel(const int* __restrict__ edges, int* __restrict__ deg, int E) {
    int e = blockIdx.x * blockDim.x + threadIdx.x;
    if (e < E) atomicAdd(&deg[edges[2 * e + 1]], 1);
}

__global__ void scan_kernel(const int* __restrict__ deg, int* __restrict__ row_ptr,
                            int* __restrict__ cursor, int n) {
    __shared__ int sums[256];
    int t = threadIdx.x;
    const int C = (n + 255) / 256;
    int lo = t * C, hi = min(lo + C, n);
    if (lo > n) lo = n;
    if (hi < lo) hi = lo;
    int s = 0;
    for (int i = lo; i < hi; ++i) s += deg[i];
    sums[t] = s;
    __syncthreads();
    for (int off = 1; off < 256; off <<= 1) {
        int v = (t >= off) ? sums[t - off] : 0;
        __syncthreads();
        sums[t] += v;
        __syncthreads();
    }
    int run = (t == 0) ? 0 : sums[t - 1];
    for (int i = lo; i < hi; ++i) {
        int d = deg[i];
        row_ptr[i] = run;
        cursor[i]  = run;
        run += d;
    }
    if (t == 255) row_ptr[n] = sums[255];
}

__global__ void scatter_kernel(const int* __restrict__ edges, int* __restrict__ cursor,
                               int* __restrict__ edge_src, int* __restrict__ edge_dst, int E) {
    int e = blockIdx.x * blockDim.x + threadIdx.x;
    if (e < E) {
        int sv = edges[2 * e], d = edges[2 * e + 1];
        int pos = atomicAdd(&cursor[d], 1);
        if (pos >= 0 && pos < E) { edge_src[pos] = sv; edge_dst[pos] = d; }
    }
}

// ---------------------------------------------------------------------------
// Per-edge softmax weight precompute (layer 1 only): pw[e*4+h] = exp(leaky(.))
// ---------------------------------------------------------------------------
template <int H>
__global__ __launch_bounds__(256) void pw_kernel(const float* __restrict__ e_s,
                                                 const float* __restrict__ e_d,
                                                 const int* __restrict__ esrc,
                                                 const int* __restrict__ edst,
                                                 float* __restrict__ pw, int E) {
    int e = blockIdx.x * blockDim.x + threadIdx.x;
    if (e >= E) return;
    int s = esrc[e], d = edst[e];
    const float* ps = e_s + (size_t)s * H;
    const float* pd = e_d + (size_t)d * H;
#pragma unroll
    for (int h = 0; h < H; ++h)
        pw[(size_t)e * H + h] = __expf(leaky(ps[h] + pd[h]));
}

// ---------------------------------------------------------------------------
// prep2 mega-kernel (block-range partitioned, sections independent):
//   blocks [0,3336)      : weight prep (see offsets inline)
//   blocks [3336,3532)   : deg[NN] = 0
//   blocks [3532,9782)   : x0 fp32 -> x0b bf16
// NOTE: 768 is NOT a power of two — never use &767 (r7 bug).
// ---------------------------------------------------------------------------
__global__ __launch_bounds__(256) void prep2(
    const float* __restrict__ W1, const float* __restrict__ R1,
    const float* __restrict__ W2, const float* __restrict__ W3,
    const float* __restrict__ R3, const float* __restrict__ a1s,
    const float* __restrict__ a1d, const float* __restrict__ a3s,
    const float* __restrict__ a3d, const float* __restrict__ x0,
    unsigned short* __restrict__ w1t, unsigned short* __restrict__ r1t,
    unsigned short* __restrict__ w2t, unsigned short* __restrict__ w3t,
    unsigned short* __restrict__ r3t, float* __restrict__ wsb,
    float* __restrict__ wdb, float* __restrict__ a3sp, float* __restrict__ a3dp,
    int* __restrict__ deg, unsigned short* __restrict__ x0b) {
    const int b = blockIdx.x, t = threadIdx.x;

    if (b >= 3532) {                         // x0 conversion
        int i = ((b - 3532) * 256 + t) * 4;
        if (i + 3 < NN * 128) {
            float4 v = *(const float4*)(x0 + i);
            ushort4 o;
            o.x = f2bf(v.x); o.y = f2bf(v.y); o.z = f2bf(v.z); o.w = f2bf(v.w);
            *(ushort4*)(x0b + i) = o;
        }
        return;
    }
    if (b >= 3336) {                         // deg zero
        int i = (b - 3336) * 256 + t;
        if (i < NN) deg[i] = 0;
        return;
    }

    int idx = b * 256 + t;
    if (idx < 65536) {                       // w1t
        int n = idx >> 7, k = idx & 127;
        w1t[idx] = f2bf(W1[k * 512 + n]);
        return;
    }
    idx -= 65536;
    if (idx < 65536) {                       // r1t
        int n = idx >> 7, k = idx & 127;
        r1t[idx] = f2bf(R1[k * 512 + n]);
        return;
    }
    idx -= 65536;
    if (idx < 262144) {                      // w2t
        int n = idx >> 9, k = idx & 511;
        w2t[idx] = f2bf(W2[(size_t)k * 512 + n]);
        return;
    }
    idx -= 262144;
    if (idx < 393216) {                      // w3t head-padded
        int np = idx >> 9, k = idx & 511;
        int h = np >> 7, u = np & 127;
        w3t[idx] = f2bf((u < 121) ? W3[(size_t)k * 726 + h * 121 + u] : 0.f);
        return;
    }
    idx -= 393216;
    if (idx < 65536) {                       // r3t
        int n = idx >> 9, k = idx & 511;
        r3t[idx] = f2bf((n < 121) ? R3[(size_t)k * 121 + n] : 0.f);
        return;
    }
    idx -= 65536;
    if (idx < 512) {                         // combine_a (layer 1)
        int h = idx >> 7, k = idx & 127;
        float s = 0.f, d = 0.f;
        for (int u = 0; u < 128; ++u) {
            float w = W1[k * 512 + h * 128 + u];
            s = fmaf(w, a1s[h * 128 + u], s);
            d = fmaf(w, a1d[h * 128 + u], d);
        }
        wsb[idx] = s;
        wdb[idx] = d;
        return;
    }
    idx -= 512;
    if (idx < 1536) {                        // a3 padding (explicit arithmetic)
        int which = (idx >= 768) ? 1 : 0;
        int j = idx - which * 768;           // j in [0,768)
        int h = j >> 7, u = j & 127;
        float val = (u < 121) ? (which ? a3d[h * 121 + u] : a3s[h * 121 + u]) : 0.f;
        if (which) a3dp[j] = val; else a3sp[j] = val;
    }
}

// ---------------------------------------------------------------------------
// GEMM + fused escore + int8 quant. 1-D grid, XCD-grouped remap (r11):
//   xcd = bid&7 owns contiguous row-blocks; NX head blocks of one row-block
//   launch back-to-back on one XCD -> A panel fetched once per XCD.
// LDS bank swizzle: chunk c' = c ^ ((row>>1)&3) on global source AND ds_read.
// Outputs: Cq int8 [M][NS]; esq float2 {e_s, scl}[M][Hl]; e_d[M][Hl].
// Head with col0==768 (layer 3): R3 residual -> fp32 resout[M][121].
// ---------------------------------------------------------------------------
__global__ __launch_bounds__(256) void gemm_esc(const unsigned short* __restrict__ A,
                                                const unsigned short* __restrict__ BT,
                                                signed char* __restrict__ Cq,
                                                float2* __restrict__ esq,
                                                float* __restrict__ e_d,
                                                const float* __restrict__ asv,
                                                const float* __restrict__ adv,
                                                float* __restrict__ resout,
                                                int M, int NS, int Hl, int NX) {
    __shared__ __align__(16) unsigned short As[128 * 32];
    __shared__ __align__(16) unsigned short Bs[128 * 32];

    // XCD-grouped block remap (bijective; MBLK=391 = 8*48+7)
    const int xcd = blockIdx.x & 7, pos = blockIdx.x >> 3;
    const int nrows = ROWQ + (xcd < ROWR ? 1 : 0);
    if (pos >= nrows * NX) return;
    const int ybase = xcd * ROWQ + min(xcd, ROWR);
    const int by = ybase + pos / NX;
    const int bx = pos - (pos / NX) * NX;

    const int t    = threadIdx.x;
    const int wave = t >> 6, lane = t & 63;
    const int wm   = (wave >> 1) * 64, wn = (wave & 1) * 64;
    const int l15  = lane & 15, q = lane >> 4;
    const int row0 = by * 128, col0 = bx * 128;

    floatx4 acc[4][4];
#pragma unroll
    for (int i = 0; i < 4; ++i)
#pragma unroll
        for (int j = 0; j < 4; ++j) acc[i][j] = (floatx4){0.f, 0.f, 0.f, 0.f};

    for (int k0 = 0; k0 < 512; k0 += 32) {
#pragma unroll
        for (int p = 0; p < 2; ++p) {
            int idx = p * 256 + t;
            int r = idx >> 2, qq = idx & 3;
            int cc = qq ^ ((r >> 1) & 3);     // bank-conflict swizzle (source side)
            int ar = row0 + r; ar = (ar < M) ? ar : (M - 1);
            unsigned short* ldsA = As + (p * 2048 + wave * 512);
            unsigned short* ldsB = Bs + (p * 2048 + wave * 512);
            gload_lds16(A  + (size_t)ar * 512 + k0 + cc * 8, ldsA);
            gload_lds16(BT + (size_t)(col0 + r) * 512 + k0 + cc * 8, ldsB);
        }
        __syncthreads();

        short8 af[4], bfr[4];
#pragma unroll
        for (int mi = 0; mi < 4; ++mi) {
            int row = wm + 16 * mi + l15;
            af[mi] = *(const short8*)&As[row * 32 + (q ^ ((row >> 1) & 3)) * 8];
        }
#pragma unroll
        for (int ni = 0; ni < 4; ++ni) {
            int row = wn + 16 * ni + l15;
            bfr[ni] = *(const short8*)&Bs[row * 32 + (q ^ ((row >> 1) & 3)) * 8];
        }
#pragma unroll
        for (int mi = 0; mi < 4; ++mi)
#pragma unroll
            for (int ni = 0; ni < 4; ++ni)
                acc[mi][ni] = __builtin_amdgcn_mfma_f32_16x16x32_bf16(af[mi], bfr[ni], acc[mi][ni], 0, 0, 0);
        __syncthreads();
    }

    if (col0 == 768) {
        // R3 residual head: fp32 store to resout[M][121], no escore/quant.
#pragma unroll
        for (int ni = 0; ni < 4; ++ni) {
            int gcl = wn + 16 * ni + l15;
            if (gcl >= 121) continue;
#pragma unroll
            for (int mi = 0; mi < 4; ++mi) {
#pragma unroll
                for (int r = 0; r < 4; ++r) {
                    int gr = row0 + wm + 16 * mi + q * 4 + r;
                    if (gr < M) resout[(size_t)gr * 121 + gcl] = acc[mi][ni][r];
                }
            }
        }
        return;
    }

    // shared reduction buffers (reuse As): sred[256] escore sums, sredm[128] rowmax
    float* sred  = (float*)As;
    int*   sredm = (int*)(sred + 256);
    if (t < 256) sred[t] = 0.f;
    if (t < 128) sredm[t] = 0;
    __syncthreads();

    float av[4], dv[4];
#pragma unroll
    for (int ni = 0; ni < 4; ++ni) {
        int gc = col0 + wn + 16 * ni + l15;
        av[ni] = asv[gc];
        dv[ni] = adv[gc];
    }
#pragma unroll
    for (int mi = 0; mi < 4; ++mi) {
#pragma unroll
        for (int r = 0; r < 4; ++r) {
            float ps = 0.f, pd = 0.f, mx = 0.f;
#pragma unroll
            for (int ni = 0; ni < 4; ++ni) {
                ps = fmaf(acc[mi][ni][r], av[ni], ps);
                pd = fmaf(acc[mi][ni][r], dv[ni], pd);
                mx = fmaxf(mx, fabsf(acc[mi][ni][r]));
            }
#pragma unroll
            for (int off = 1; off < 16; off <<= 1) {
                ps += __shfl_xor(ps, off);
                pd += __shfl_xor(pd, off);
                mx = fmaxf(mx, __shfl_xor(mx, off));
            }
            if (l15 == 0) {
                int rloc = wm + 16 * mi + 4 * q + r;
                atomicAdd(&sred[rloc * 2 + 0], ps);
                atomicAdd(&sred[rloc * 2 + 1], pd);
                atomicMax(&sredm[rloc], __float_as_int(mx));
            }
        }
    }
    __syncthreads();

    // int8 store
#pragma unroll
    for (int mi = 0; mi < 4; ++mi) {
#pragma unroll
        for (int r = 0; r < 4; ++r) {
            int rloc = wm + 16 * mi + 4 * q + r;
            float rm = fmaxf(__int_as_float(sredm[rloc]), 1e-20f);
            float iq = 127.f / rm;
            int gr = row0 + rloc;
#pragma unroll
            for (int ni = 0; ni < 4; ++ni) {
                int gc = col0 + wn + 16 * ni + l15;
                if (gr < M)
                    Cq[(size_t)gr * NS + gc] = (signed char)(int)rintf(acc[mi][ni][r] * iq);
            }
        }
    }

    if (t < 128) {
        int gr = row0 + t;
        if (gr < M) {
            float2 ev;
            ev.x = sred[t * 2 + 0];
            ev.y = fmaxf(__int_as_float(sredm[t]), 1e-20f) * (1.f / 127.f);
            esq[(size_t)gr * Hl + bx] = ev;
            e_d[(size_t)gr * Hl + bx] = sred[t * 2 + 1];
        }
    }
}

// ---------------------------------------------------------------------------
// Layer-1 fused GEMM: x1 = elu(aggx_h @ W1_h + x0 @ R1_h), blockIdx.x = head.
// ---------------------------------------------------------------------------
__global__ __launch_bounds__(256) void gemm_l1(const unsigned short* __restrict__ aggx,
                                               const unsigned short* __restrict__ w1t,
                                               const unsigned short* __restrict__ x0b,
                                               const unsigned short* __restrict__ r1t,
                                               unsigned short* __restrict__ C, int M) {
    __shared__ __align__(16) unsigned short As[128 * 32];
    __shared__ __align__(16) unsigned short Bs[128 * 32];

    const int t    = threadIdx.x;
    const int wave = t >> 6, lane = t & 63;
    const int wm   = (wave >> 1) * 64, wn = (wave & 1) * 64;
    const int l15  = lane & 15, q = lane >> 4;
    const int row0 = blockIdx.y * 128;
    const int head = blockIdx.x;
    const int ccol = head * 128;

    floatx4 acc[4][4];
#pragma unroll
    for (int i = 0; i < 4; ++i)
#pragma unroll
        for (int j = 0; j < 4; ++j) acc[i][j] = (floatx4){0.f, 0.f, 0.f, 0.f};

    for (int ph = 0; ph < 2; ++ph) {
        const unsigned short* A  = ph ? x0b : (aggx + ccol);
        const int AS             = ph ? 128 : 512;
        const unsigned short* BT = (ph ? r1t : w1t) + (size_t)ccol * 128;

        for (int k0 = 0; k0 < 128; k0 += 32) {
#pragma unroll
            for (int p = 0; p < 2; ++p) {
                int idx = p * 256 + t;
                int r = idx >> 2, qq = idx & 3;
                int ar = row0 + r; ar = (ar < M) ? ar : (M - 1);
                unsigned short* ldsA = As + (p * 2048 + wave * 512);
                unsigned short* ldsB = Bs + (p * 2048 + wave * 512);
                gload_lds16(A  + (size_t)ar * AS + k0 + qq * 8, ldsA);
                gload_lds16(BT + (size_t)r * 128 + k0 + qq * 8, ldsB);
            }
            __syncthreads();

            short8 af[4], bfr[4];
#pragma unroll
            for (int mi = 0; mi < 4; ++mi) af[mi]  = *(const short8*)&As[(wm + 16 * mi + l15) * 32 + q * 8];
#pragma unroll
            for (int ni = 0; ni < 4; ++ni) bfr[ni] = *(const short8*)&Bs[(wn + 16 * ni + l15) * 32 + q * 8];
#pragma unroll
            for (int mi = 0; mi < 4; ++mi)
#pragma unroll
                for (int ni = 0; ni < 4; ++ni)
                    acc[mi][ni] = __builtin_amdgcn_mfma_f32_16x16x32_bf16(af[mi], bfr[ni], acc[mi][ni], 0, 0, 0);
            __syncthreads();
        }
    }

#pragma unroll
    for (int ni = 0; ni < 4; ++ni) {
        int gc = ccol + wn + 16 * ni + l15;
#pragma unroll
        for (int mi = 0; mi < 4; ++mi) {
#pragma unroll
            for (int r = 0; r < 4; ++r) {
                int gr = row0 + wm + 16 * mi + q * 4 + r;
                if (gr < M) {
                    float z = acc[mi][ni][r];
                    z = (z > 0.f) ? z : (__expf(z) - 1.f);   // elu
                    C[(size_t)gr * 512 + gc] = f2bf(z);
                }
            }
        }
    }
}

// ---------------------------------------------------------------------------
// escore over x (layer 1): e_s[n,h] = x[n] . ws[h], 128-dim, 4 heads.
// ---------------------------------------------------------------------------
__global__ __launch_bounds__(256) void escore_x(const unsigned short* __restrict__ x,
                                                const float* __restrict__ ws,
                                                const float* __restrict__ wd,
                                                float* __restrict__ e_s,
                                                float* __restrict__ e_d) {
    const int wave = threadIdx.x >> 6, lane = threadIdx.x & 63;
    const int n = blockIdx.x * 4 + wave;
    const int h = lane >> 4, seg = lane & 15;

    short8 hv = *(const short8*)(x + (size_t)n * 128 + seg * 8);
    float4 w0 = *(const float4*)(ws + h * 128 + seg * 8);
    float4 w1 = *(const float4*)(ws + h * 128 + seg * 8 + 4);
    float4 d0 = *(const float4*)(wd + h * 128 + seg * 8);
    float4 d1 = *(const float4*)(wd + h * 128 + seg * 8 + 4);
    float av[8] = {w0.x, w0.y, w0.z, w0.w, w1.x, w1.y, w1.z, w1.w};
    float dv[8] = {d0.x, d0.y, d0.z, d0.w, d1.x, d1.y, d1.z, d1.w};

    float ps = 0.f, pd = 0.f;
#pragma unroll
    for (int j = 0; j < 8; ++j) {
        float xv = bf2f((unsigned short)hv[j]);
        ps = fmaf(xv, av[j], ps);
        pd = fmaf(xv, dv[j], pd);
    }
#pragma unroll
    for (int off = 1; off < 16; off <<= 1) {
        ps += __shfl_xor(ps, off);
        pd += __shfl_xor(pd, off);
    }
    if (seg == 0) {
        e_s[(size_t)n * 4 + h] = ps;
        e_d[(size_t)n * 4 + h] = pd;
    }
}

// ---------------------------------------------------------------------------
// Layer-1 x-aggregation: aggx[n,h,u] = (1/den_h) sum_e pw[e,h] x[src_e, u].
// ---------------------------------------------------------------------------
__global__ __launch_bounds__(256) void agg_x512(const unsigned short* __restrict__ x,
                                                const float* __restrict__ pw,
                                                const int* __restrict__ rowp,
                                                const int* __restrict__ esrc,
                                                unsigned short* __restrict__ aggx) {
    const int wave = threadIdx.x >> 6, lane = threadIdx.x & 63;
    const int n = blockIdx.x * 4 + wave;
    const int lid = lane & 31, half = lane >> 5;
    const int beg = rowp[n], end = rowp[n + 1];

    float den[4] = {0.f, 0.f, 0.f, 0.f};
    float acc[4][4];
#pragma unroll
    for (int h = 0; h < 4; ++h)
#pragma unroll
        for (int j = 0; j < 4; ++j) acc[h][j] = 0.f;

    int e = beg;
    for (; e + 8 <= end; e += 8) {
        int s[4];
        float4 p[4];
        short4v xr[4];
#pragma unroll
        for (int k = 0; k < 4; ++k) s[k] = esrc[e + 2 * k + half];
#pragma unroll
        for (int k = 0; k < 4; ++k) p[k] = *(const float4*)(pw + (size_t)(e + 2 * k + half) * 4);
#pragma unroll
        for (int k = 0; k < 4; ++k) xr[k] = *(const short4v*)(x + (size_t)s[k] * 128 + lid * 4);
#pragma unroll
        for (int k = 0; k < 4; ++k) {
            den[0] += p[k].x; den[1] += p[k].y; den[2] += p[k].z; den[3] += p[k].w;
#pragma unroll
            for (int j = 0; j < 4; ++j) {
                float xf = bf2f((unsigned short)xr[k][j]);
                acc[0][j] = fmaf(p[k].x, xf, acc[0][j]);
                acc[1][j] = fmaf(p[k].y, xf, acc[1][j]);
                acc[2][j] = fmaf(p[k].z, xf, acc[2][j]);
                acc[3][j] = fmaf(p[k].w, xf, acc[3][j]);
            }
        }
    }
    for (; e < end; e += 2) {
        int idx = e + half;
        if (idx < end) {
            int s = esrc[idx];
            float4 p = *(const float4*)(pw + (size_t)idx * 4);
            short4v xr = *(const short4v*)(x + (size_t)s * 128 + lid * 4);
            den[0] += p.x; den[1] += p.y; den[2] += p.z; den[3] += p.w;
#pragma unroll
            for (int j = 0; j < 4; ++j) {
                float xf = bf2f((unsigned short)xr[j]);
                acc[0][j] = fmaf(p.x, xf, acc[0][j]);
                acc[1][j] = fmaf(p.y, xf, acc[1][j]);
                acc[2][j] = fmaf(p.z, xf, acc[2][j]);
                acc[3][j] = fmaf(p.w, xf, acc[3][j]);
            }
        }
    }

    // combine half-waves
#pragma unroll
    for (int h = 0; h < 4; ++h) {
        den[h] += __shfl_xor(den[h], 32);
#pragma unroll
        for (int j = 0; j < 4; ++j) acc[h][j] += __shfl_xor(acc[h][j], 32);
    }
    if (half == 0) {
#pragma unroll
        for (int h = 0; h < 4; ++h) {
            const float inv = 1.f / fmaxf(den[h], 1e-9f);
            ushort4 o;
            o.x = f2bf(acc[h][0] * inv);
            o.y = f2bf(acc[h][1] * inv);
            o.z = f2bf(acc[h][2] * inv);
            o.w = f2bf(acc[h][3] * inv);
            *(ushort4*)(aggx + (size_t)n * 512 + h * 128 + lid * 4) = o;
        }
    }
}

// ---------------------------------------------------------------------------
// Wave-per-node aggregation, layer 2, int8 hbuf stride 512 + packed
// esq {e_s, scl} float2. den uses unscaled p; acc uses p*scl. 8-edge pipeline.
// ---------------------------------------------------------------------------
__global__ __launch_bounds__(256) void agg_q512(const signed char* __restrict__ hq,
                                                const float2* __restrict__ esq,
                                                const float* __restrict__ ed,
                                                const int* __restrict__ rowp,
                                                const int* __restrict__ esrc,
                                                const unsigned short* res,
                                                unsigned short* out) {
    const int wave = threadIdx.x >> 6, lane = threadIdx.x & 63;
    const int n = blockIdx.x * 4 + wave;      // grid*4 == NN exactly
    const int h = lane >> 4;
    const int beg = rowp[n], end = rowp[n + 1];
    const float edh = ed[(size_t)n * 4 + h];

    float den = 0.f;
    float acc[8];
#pragma unroll
    for (int j = 0; j < 8; ++j) acc[j] = 0.f;

    int e = beg;
    for (; e + 8 <= end; e += 8) {
        int s[8];
#pragma unroll
        for (int k = 0; k < 8; ++k) s[k] = esrc[e + k];
        schar8 r[8];
#pragma unroll
        for (int k = 0; k < 8; ++k) r[k] = *(const schar8*)(hq + (size_t)s[k] * 512 + lane * 8);
        float p[8], qv[8];
#pragma unroll
        for (int k = 0; k < 8; ++k) {
            float2 ev = esq[(size_t)s[k] * 4 + h];
            float pv = __expf(leaky(ev.x + edh));
            p[k] = pv;
            qv[k] = pv * ev.y;
        }
#pragma unroll
        for (int k = 0; k < 8; ++k) den += p[k];
#pragma unroll
        for (int j = 0; j < 8; ++j) {
            float a = acc[j];
#pragma unroll
            for (int k = 0; k < 8; ++k) a = fmaf(qv[k], (float)r[k][j], a);
            acc[j] = a;
        }
    }
    for (; e < end; ++e) {
        int s0 = esrc[e];
        schar8 r0 = *(const schar8*)(hq + (size_t)s0 * 512 + lane * 8);
        float2 ev = esq[(size_t)s0 * 4 + h];
        float p0 = __expf(leaky(ev.x + edh));
        float q0 = p0 * ev.y;
        den += p0;
#pragma unroll
        for (int j = 0; j < 8; ++j) acc[j] = fmaf(q0, (float)r0[j], acc[j]);
    }

    const float inv = 1.f / fmaxf(den, 1e-9f);
    short8 rv = *(const short8*)(res + (size_t)n * 512 + lane * 8);
    short8 ov;
#pragma unroll
    for (int j = 0; j < 8; ++j) {
        float z = acc[j] * inv + bf2f((unsigned short)rv[j]);
        z = (z > 0.f) ? z : (__expf(z) - 1.f);   // elu
        ov[j] = (short)f2bf(z);
    }
    *(short8*)(out + (size_t)n * 512 + lane * 8) = ov;
}

// ---------------------------------------------------------------------------
// Wave-per-node aggregation, layer 3, int8 stride 768, packed esq.
// Chunk0 (heads 0-3): all 64 lanes, 4 edges/group. Chunk1 (heads 4,5):
// balanced across wave halves, 2 edges each, reduced via shfl_xor(32).
// r13 FIX (rule #20): edge selects use explicit cndmask (half ? s[2] : s[0]),
// NOT runtime array indexing s[half*2] (which demoted s[] to scratch:
// VGPR 48->36, BW 3.2->2.1 TB/s, dur 124->177 us).
// ---------------------------------------------------------------------------
__global__ __launch_bounds__(256) void agg_q768(const signed char* __restrict__ hq,
                                                const float2* __restrict__ esq,
                                                const float* __restrict__ ed,
                                                const int* __restrict__ rowp,
                                                const int* __restrict__ esrc,
                                                const float* res,
                                                float* out) {
    __shared__ float s_vals[4][768];
    const int wave = threadIdx.x >> 6, lane = threadIdx.x & 63;
    const int n = blockIdx.x * 4 + wave;
    const int beg = rowp[n], end = rowp[n + 1];

    const int h0 = lane >> 4;                  // chunk0 head (0..3)
    const int l31 = lane & 31, half = lane >> 5;
    const int h1 = 4 + (l31 >> 4);             // chunk1 head (4,5)
    const float edh0 = ed[(size_t)n * 6 + h0];
    const float edh1 = ed[(size_t)n * 6 + h1];

    float den0 = 0.f, den1 = 0.f;
    float acc0[8], acc1[8];
#pragma unroll
    for (int j = 0; j < 8; ++j) { acc0[j] = 0.f; acc1[j] = 0.f; }

    int e = beg;
    for (; e + 4 <= end; e += 4) {
        int s0e = esrc[e], s1e = esrc[e + 1], s2e = esrc[e + 2], s3e = esrc[e + 3];
        // chunk0: all lanes, all 4 edges
        schar8 r0 = *(const schar8*)(hq + (size_t)s0e * 768 + lane * 8);
        schar8 r1 = *(const schar8*)(hq + (size_t)s1e * 768 + lane * 8);
        schar8 r2 = *(const schar8*)(hq + (size_t)s2e * 768 + lane * 8);
        schar8 r3 = *(const schar8*)(hq + (size_t)s3e * 768 + lane * 8);
        float2 e0 = esq[(size_t)s0e * 6 + h0];
        float2 e1 = esq[(size_t)s1e * 6 + h0];
        float2 e2 = esq[(size_t)s2e * 6 + h0];
        float2 e3 = esq[(size_t)s3e * 6 + h0];
        float p0 = __expf(leaky(e0.x + edh0));
        float p1 = __expf(leaky(e1.x + edh0));
        float p2 = __expf(leaky(e2.x + edh0));
        float p3 = __expf(leaky(e3.x + edh0));
        float q0 = p0 * e0.y, q1 = p1 * e1.y, q2 = p2 * e2.y, q3 = p3 * e3.y;
        den0 += (p0 + p1) + (p2 + p3);
#pragma unroll
        for (int j = 0; j < 8; ++j)
            acc0[j] = fmaf(q0, (float)r0[j],
                      fmaf(q1, (float)r1[j],
                      fmaf(q2, (float)r2[j],
                      fmaf(q3, (float)r3[j], acc0[j]))));
        // chunk1: this half's 2 edges — explicit cndmask selects (NO array idx)
        int sA = half ? s2e : s0e;
        int sB = half ? s3e : s1e;
        schar8 rA = *(const schar8*)(hq + (size_t)sA * 768 + 512 + l31 * 8);
        schar8 rB = *(const schar8*)(hq + (size_t)sB * 768 + 512 + l31 * 8);
        float2 evA = esq[(size_t)sA * 6 + h1];
        float2 evB = esq[(size_t)sB * 6 + h1];
        float pA = __expf(leaky(evA.x + edh1));
        float pB = __expf(leaky(evB.x + edh1));
        float qA = pA * evA.y, qB = pB * evB.y;
        den1 += pA + pB;
#pragma unroll
        for (int j = 0; j < 8; ++j)
            acc1[j] = fmaf(qA, (float)rA[j], fmaf(qB, (float)rB[j], acc1[j]));
    }
    for (; e < end; ++e) {
        int s = esrc[e];
        schar8 r0 = *(const schar8*)(hq + (size_t)s * 768 + lane * 8);
        float2 ev0 = esq[(size_t)s * 6 + h0];
        float p0 = __expf(leaky(ev0.x + edh0));
        float q0 = p0 * ev0.y;
        den0 += p0;
#pragma unroll
        for (int j = 0; j < 8; ++j) acc0[j] = fmaf(q0, (float)r0[j], acc0[j]);
        if (half == 0) {                       // tail chunk1: half 0 only
            schar8 r1 = *(const schar8*)(hq + (size_t)s * 768 + 512 + l31 * 8);
            float2 ev1 = esq[(size_t)s * 6 + h1];
            float p1 = __expf(leaky(ev1.x + edh1));
            float q1 = p1 * ev1.y;
            den1 += p1;
#pragma unroll
            for (int j = 0; j < 8; ++j) acc1[j] = fmaf(q1, (float)r1[j], acc1[j]);
        }
    }

    // reduce chunk1 across halves
    den1 += __shfl_xor(den1, 32);
#pragma unroll
    for (int j = 0; j < 8; ++j) acc1[j] += __shfl_xor(acc1[j], 32);

    const float inv0 = 1.f / fmaxf(den0, 1e-9f);
#pragma unroll
    for (int j = 0; j < 8; ++j) s_vals[wave][lane * 8 + j] = acc0[j] * inv0;
    if (lane < 32) {
        const float inv1 = 1.f / fmaxf(den1, 1e-9f);
#pragma unroll
        for (int j = 0; j < 8; ++j) s_vals[wave][512 + l31 * 8 + j] = acc1[j] * inv1;
    }
    __syncthreads();

    for (int u = lane; u < 121; u += 64) {
        float sum = 0.f;
#pragma unroll
        for (int hh = 0; hh < 6; ++hh) sum += s_vals[wave][hh * 128 + u];
        float v = sum * (1.f / 6.f) + res[(size_t)n * 121 + u];
        __builtin_nontemporal_store(v, out + (size_t)n * 121 + u);
    }
}

// ---------------------------------------------------------------------------
// Launch
// ---------------------------------------------------------------------------
static inline size_t align256(size_t x) { return (x + 255) & ~(size_t)255; }

extern "C" void kernel_launch(void* const* d_in, const int* in_sizes, int n_in,
                              void* d_out, int out_size, void* d_ws, size_t ws_size,
                              hipStream_t stream) {
    const float* x0  = (const float*)d_in[0];   // [50000,128] fp32
    const int* edges = (const int*)d_in[1];     // [800000,2] int32
    const float* W1  = (const float*)d_in[2];   // [128,512]
    const float* a1s = (const float*)d_in[3];
    const float* a1d = (const float*)d_in[4];
    const float* R1  = (const float*)d_in[5];   // [128,512]
    const float* W2  = (const float*)d_in[6];   // [512,512]
    const float* a2s = (const float*)d_in[7];
    const float* a2d = (const float*)d_in[8];
    const float* W3  = (const float*)d_in[9];   // [512,726]
    const float* a3s = (const float*)d_in[10];
    const float* a3d = (const float*)d_in[11];
    const float* R3  = (const float*)d_in[12];  // [512,121]
    float* out = (float*)d_out;                 // [50000,121] fp32

    // workspace carve (~160 MB). w3t/r3t MUST stay contiguous (gemm_esc R3 head).
    char* w = (char*)d_ws;
    size_t off = 0;
    unsigned short* hbuf = (unsigned short*)(w + off); off = align256(off + (size_t)NN * 768 * 2);
    unsigned short* x1   = (unsigned short*)(w + off); off = align256(off + (size_t)NN * 512 * 2);
    float* es  = (float*)(w + off); off = align256(off + (size_t)NN * 6 * 4);
    float* ed  = (float*)(w + off); off = align256(off + (size_t)NN * 6 * 4);
    int* rowp  = (int*)(w + off);   off = align256(off + (size_t)(NN + 1) * 4);
    int* esrc  = (int*)(w + off);   off = align256(off + (size_t)NE * 4);
    int* edst  = (int*)(w + off);   off = align256(off + (size_t)NE * 4);
    float* pw  = (float*)(w + off); off = align256(off + (size_t)NE * 4 * 4 + 256);
    unsigned short* w1t = (unsigned short*)(w + off); off = align256(off + (size_t)512 * 128 * 2);
    unsigned short* r1t = (unsigned short*)(w + off); off = align256(off + (size_t)512 * 128 * 2);
    unsigned short* w2t = (unsigned short*)(w + off); off = align256(off + (size_t)512 * 512 * 2);
    unsigned short* w3t = (unsigned short*)(w + off); off = align256(off + (size_t)768 * 512 * 2);
    unsigned short* r3t = (unsigned short*)(w + off); off = align256(off + (size_t)128 * 512 * 2);
    float* wsb = (float*)(w + off); off = align256(off + (size_t)512 * 4);
    float* wdb = (float*)(w + off); off = align256(off + (size_t)512 * 4);
    float* a3sp = (float*)(w + off); off = align256(off + (size_t)768 * 4);
    float* a3dp = (float*)(w + off); off = align256(off + (size_t)768 * 4);
    float2* esq = (float2*)(w + off); off = align256(off + (size_t)NN * 6 * 8);
    int* deg = (int*)es;                     // overlay: dead after CSR build
    int* cur = (int*)ed;
    // layer-1 overlays inside hbuf (hbuf not used until layer-2 GEMM writes it):
    unsigned short* x0b  = hbuf;                          // [NN,128] bf16 = 12.8 MB
    unsigned short* aggx = hbuf + (size_t)NN * 128;       // [NN,512] bf16 = 51.2 MB
    signed char* hq = (signed char*)hbuf;                 // int8 views (L2: 25.6 MB, L3: 38.4 MB)
    (void)ws_size;

    const int EB = (NE + 255) / 256;
    const int MB = MBLK;               // 391
    const int AB = NN / 4;             // 12500 blocks, 4 waves each

    // --- prep (weights + deg zero + x0 conversion, one dispatch) ---
    prep2<<<9782, 256, 0, stream>>>(W1, R1, W2, W3, R3, a1s, a1d, a3s, a3d, x0,
                                    w1t, r1t, w2t, w3t, r3t, wsb, wdb, a3sp, a3dp,
                                    deg, x0b);

    // --- CSR build ---
    deg_kernel<<<EB, 256, 0, stream>>>(edges, deg, NE);
    scan_kernel<<<1, 256, 0, stream>>>(deg, rowp, cur, NN);
    scatter_kernel<<<EB, 256, 0, stream>>>(edges, cur, esrc, edst, NE);

    // --- Layer 1 (x-aggregation + fused dual-K GEMM) ---
    escore_x<<<AB, 256, 0, stream>>>(x0b, wsb, wdb, es, ed);
    pw_kernel<4><<<EB, 256, 0, stream>>>(es, ed, esrc, edst, pw, NE);
    agg_x512<<<AB, 256, 0, stream>>>(x0b, pw, rowp, esrc, aggx);
    gemm_l1<<<dim3(4, MB), 256, 0, stream>>>(aggx, w1t, x0b, r1t, x1, NN);

    // --- Layer 2: GEMM + escore + int8 quant (XCD-grouped grid 8*49*4=1568) ---
    gemm_esc<<<8 * 49 * 4, 256, 0, stream>>>(x1, w2t, hq, esq, ed,
                                             a2s, a2d, out, NN, 512, 4, 4);
    agg_q512<<<AB, 256, 0, stream>>>(hq, esq, ed, rowp, esrc, x1, x1);

    // --- Layer 3: GEMM + escore + int8 quant + R3 head (grid 8*49*7=2744) ---
    gemm_esc<<<8 * 49 * 7, 256, 0, stream>>>(x1, w3t, hq, esq, ed,
                                             a3sp, a3dp, out, NN, 768, 6, 7);
    agg_q768<<<AB, 256, 0, stream>>>(hq, esq, ed, rowp, esrc, out, out);
}

// Round 15
// 788.850 us; speedup vs baseline: 1.0641x; 1.0140x over previous
//
#include <hip/hip_runtime.h>
#include <math.h>

// Problem constants
#define NN 50000
#define NE 800000
#define MBLK 391           // (NN+127)/128 row blocks
#define ROWQ 48            // MBLK/8
#define ROWR 7             // MBLK%8

typedef __attribute__((ext_vector_type(8))) short  short8;   // 8 bf16 (4 VGPRs)
typedef __attribute__((ext_vector_type(4))) short  short4v;  // 4 bf16
typedef __attribute__((ext_vector_type(4))) float  floatx4;  // MFMA acc
typedef signed char schar8 __attribute__((ext_vector_type(8)));  // 8 int8

// bf16 bits <-> float helpers
__device__ __forceinline__ float bf2f(unsigned short u) {
    union { unsigned int i; float f; } v; v.i = ((unsigned int)u) << 16; return v.f;
}
__device__ __forceinline__ unsigned short f2bf(float f) {
    union { float f; unsigned int i; } v; v.f = f;
    unsigned int i = v.i;
    i += 0x7FFFu + ((i >> 16) & 1u);   // round to nearest even
    return (unsigned short)(i >> 16);
}

__device__ __forceinline__ float leaky(float v) { return (v > 0.f) ? v : 0.2f * v; }

// async 16B global -> LDS (gfx950 global_load_lds_dwordx4)
__device__ __forceinline__ void gload_lds16(const unsigned short* g, unsigned short* l) {
    __builtin_amdgcn_global_load_lds(
        (const __attribute__((address_space(1))) unsigned int*)g,
        (__attribute__((address_space(3))) unsigned int*)l, 16, 0, 0);
}

// ---------------------------------------------------------------------------
// CSR build
// ---------------------------------------------------------------------------
__global__ void deg_kernel(const int* __restrict__ edges, int* __restrict__ deg, int E) {
    int e = blockIdx.x * blockDim.x + threadIdx.x;
    if (e < E) atomicAdd(&deg[edges[2 * e + 1]], 1);
}

__global__ void scan_kernel(const int* __restrict__ deg, int* __restrict__ row_ptr,
                            int* __restrict__ cursor, int n) {
    __shared__ int sums[256];
    int t = threadIdx.x;
    const int C = (n + 255) / 256;
    int lo = t * C, hi = min(lo + C, n);
    if (lo > n) lo = n;
    if (hi < lo) hi = lo;
    int s = 0;
    for (int i = lo; i < hi; ++i) s += deg[i];
    sums[t] = s;
    __syncthreads();
    for (int off = 1; off < 256; off <<= 1) {
        int v = (t >= off) ? sums[t - off] : 0;
        __syncthreads();
        sums[t] += v;
        __syncthreads();
    }
    int run = (t == 0) ? 0 : sums[t - 1];
    for (int i = lo; i < hi; ++i) {
        int d = deg[i];
        row_ptr[i] = run;
        cursor[i]  = run;
        run += d;
    }
    if (t == 255) row_ptr[n] = sums[255];
}

__global__ void scatter_kernel(const int* __restrict__ edges, int* __restrict__ cursor,
                               int* __restrict__ edge_src, int* __restrict__ edge_dst, int E) {
    int e = blockIdx.x * blockDim.x + threadIdx.x;
    if (e < E) {
        int sv = edges[2 * e], d = edges[2 * e + 1];
        int pos = atomicAdd(&cursor[d], 1);
        if (pos >= 0 && pos < E) { edge_src[pos] = sv; edge_dst[pos] = d; }
    }
}

// ---------------------------------------------------------------------------
// Per-edge softmax weight precompute (layer 1 only): pw[e*4+h] = exp(leaky(.))
// ---------------------------------------------------------------------------
template <int H>
__global__ __launch_bounds__(256) void pw_kernel(const float* __restrict__ e_s,
                                                 const float* __restrict__ e_d,
                                                 const int* __restrict__ esrc,
                                                 const int* __restrict__ edst,
                                                 float* __restrict__ pw, int E) {
    int e = blockIdx.x * blockDim.x + threadIdx.x;
    if (e >= E) return;
    int s = esrc[e], d = edst[e];
    const float* ps = e_s + (size_t)s * H;
    const float* pd = e_d + (size_t)d * H;
#pragma unroll
    for (int h = 0; h < H; ++h)
        pw[(size_t)e * H + h] = __expf(leaky(ps[h] + pd[h]));
}

// ---------------------------------------------------------------------------
// prep2 mega-kernel (block-range partitioned, sections independent):
//   blocks [0,3336)      : weight prep (see offsets inline)
//   blocks [3336,3532)   : deg[NN] = 0
//   blocks [3532,9782)   : x0 fp32 -> x0b bf16
// NOTE: 768 is NOT a power of two — never use &767 (r7 bug).
// ---------------------------------------------------------------------------
__global__ __launch_bounds__(256) void prep2(
    const float* __restrict__ W1, const float* __restrict__ R1,
    const float* __restrict__ W2, const float* __restrict__ W3,
    const float* __restrict__ R3, const float* __restrict__ a1s,
    const float* __restrict__ a1d, const float* __restrict__ a3s,
    const float* __restrict__ a3d, const float* __restrict__ x0,
    unsigned short* __restrict__ w1t, unsigned short* __restrict__ r1t,
    unsigned short* __restrict__ w2t, unsigned short* __restrict__ w3t,
    unsigned short* __restrict__ r3t, float* __restrict__ wsb,
    float* __restrict__ wdb, float* __restrict__ a3sp, float* __restrict__ a3dp,
    int* __restrict__ deg, unsigned short* __restrict__ x0b) {
    const int b = blockIdx.x, t = threadIdx.x;

    if (b >= 3532) {                         // x0 conversion
        int i = ((b - 3532) * 256 + t) * 4;
        if (i + 3 < NN * 128) {
            float4 v = *(const float4*)(x0 + i);
            ushort4 o;
            o.x = f2bf(v.x); o.y = f2bf(v.y); o.z = f2bf(v.z); o.w = f2bf(v.w);
            *(ushort4*)(x0b + i) = o;
        }
        return;
    }
    if (b >= 3336) {                         // deg zero
        int i = (b - 3336) * 256 + t;
        if (i < NN) deg[i] = 0;
        return;
    }

    int idx = b * 256 + t;
    if (idx < 65536) {                       // w1t
        int n = idx >> 7, k = idx & 127;
        w1t[idx] = f2bf(W1[k * 512 + n]);
        return;
    }
    idx -= 65536;
    if (idx < 65536) {                       // r1t
        int n = idx >> 7, k = idx & 127;
        r1t[idx] = f2bf(R1[k * 512 + n]);
        return;
    }
    idx -= 65536;
    if (idx < 262144) {                      // w2t
        int n = idx >> 9, k = idx & 511;
        w2t[idx] = f2bf(W2[(size_t)k * 512 + n]);
        return;
    }
    idx -= 262144;
    if (idx < 393216) {                      // w3t head-padded
        int np = idx >> 9, k = idx & 511;
        int h = np >> 7, u = np & 127;
        w3t[idx] = f2bf((u < 121) ? W3[(size_t)k * 726 + h * 121 + u] : 0.f);
        return;
    }
    idx -= 393216;
    if (idx < 65536) {                       // r3t
        int n = idx >> 9, k = idx & 511;
        r3t[idx] = f2bf((n < 121) ? R3[(size_t)k * 121 + n] : 0.f);
        return;
    }
    idx -= 65536;
    if (idx < 512) {                         // combine_a (layer 1)
        int h = idx >> 7, k = idx & 127;
        float s = 0.f, d = 0.f;
        for (int u = 0; u < 128; ++u) {
            float w = W1[k * 512 + h * 128 + u];
            s = fmaf(w, a1s[h * 128 + u], s);
            d = fmaf(w, a1d[h * 128 + u], d);
        }
        wsb[idx] = s;
        wdb[idx] = d;
        return;
    }
    idx -= 512;
    if (idx < 1536) {                        // a3 padding (explicit arithmetic)
        int which = (idx >= 768) ? 1 : 0;
        int j = idx - which * 768;           // j in [0,768)
        int h = j >> 7, u = j & 127;
        float val = (u < 121) ? (which ? a3d[h * 121 + u] : a3s[h * 121 + u]) : 0.f;
        if (which) a3dp[j] = val; else a3sp[j] = val;
    }
}

// ---------------------------------------------------------------------------
// GEMM + fused escore + int8 quant. 1-D grid, XCD-grouped remap (r11):
//   xcd = bid&7 owns contiguous row-blocks; NX head blocks of one row-block
//   launch back-to-back on one XCD -> A panel fetched once per XCD.
// LDS bank swizzle: chunk c' = c ^ ((row>>1)&3) on global source AND ds_read.
// Outputs: Cq int8 [M][NS]; esq float2 {e_s, scl}[M][Hl]; e_d[M][Hl].
// Head with col0==768 (layer 3): R3 residual -> fp32 resout[M][121].
// ---------------------------------------------------------------------------
__global__ __launch_bounds__(256) void gemm_esc(const unsigned short* __restrict__ A,
                                                const unsigned short* __restrict__ BT,
                                                signed char* __restrict__ Cq,
                                                float2* __restrict__ esq,
                                                float* __restrict__ e_d,
                                                const float* __restrict__ asv,
                                                const float* __restrict__ adv,
                                                float* __restrict__ resout,
                                                int M, int NS, int Hl, int NX) {
    __shared__ __align__(16) unsigned short As[128 * 32];
    __shared__ __align__(16) unsigned short Bs[128 * 32];

    // XCD-grouped block remap (bijective; MBLK=391 = 8*48+7)
    const int xcd = blockIdx.x & 7, pos = blockIdx.x >> 3;
    const int nrows = ROWQ + (xcd < ROWR ? 1 : 0);
    if (pos >= nrows * NX) return;
    const int ybase = xcd * ROWQ + min(xcd, ROWR);
    const int by = ybase + pos / NX;
    const int bx = pos - (pos / NX) * NX;

    const int t    = threadIdx.x;
    const int wave = t >> 6, lane = t & 63;
    const int wm   = (wave >> 1) * 64, wn = (wave & 1) * 64;
    const int l15  = lane & 15, q = lane >> 4;
    const int row0 = by * 128, col0 = bx * 128;

    floatx4 acc[4][4];
#pragma unroll
    for (int i = 0; i < 4; ++i)
#pragma unroll
        for (int j = 0; j < 4; ++j) acc[i][j] = (floatx4){0.f, 0.f, 0.f, 0.f};

    for (int k0 = 0; k0 < 512; k0 += 32) {
#pragma unroll
        for (int p = 0; p < 2; ++p) {
            int idx = p * 256 + t;
            int r = idx >> 2, qq = idx & 3;
            int cc = qq ^ ((r >> 1) & 3);     // bank-conflict swizzle (source side)
            int ar = row0 + r; ar = (ar < M) ? ar : (M - 1);
            unsigned short* ldsA = As + (p * 2048 + wave * 512);
            unsigned short* ldsB = Bs + (p * 2048 + wave * 512);
            gload_lds16(A  + (size_t)ar * 512 + k0 + cc * 8, ldsA);
            gload_lds16(BT + (size_t)(col0 + r) * 512 + k0 + cc * 8, ldsB);
        }
        __syncthreads();

        short8 af[4], bfr[4];
#pragma unroll
        for (int mi = 0; mi < 4; ++mi) {
            int row = wm + 16 * mi + l15;
            af[mi] = *(const short8*)&As[row * 32 + (q ^ ((row >> 1) & 3)) * 8];
        }
#pragma unroll
        for (int ni = 0; ni < 4; ++ni) {
            int row = wn + 16 * ni + l15;
            bfr[ni] = *(const short8*)&Bs[row * 32 + (q ^ ((row >> 1) & 3)) * 8];
        }
#pragma unroll
        for (int mi = 0; mi < 4; ++mi)
#pragma unroll
            for (int ni = 0; ni < 4; ++ni)
                acc[mi][ni] = __builtin_amdgcn_mfma_f32_16x16x32_bf16(af[mi], bfr[ni], acc[mi][ni], 0, 0, 0);
        __syncthreads();
    }

    if (col0 == 768) {
        // R3 residual head: fp32 store to resout[M][121], no escore/quant.
#pragma unroll
        for (int ni = 0; ni < 4; ++ni) {
            int gcl = wn + 16 * ni + l15;
            if (gcl >= 121) continue;
#pragma unroll
            for (int mi = 0; mi < 4; ++mi) {
#pragma unroll
                for (int r = 0; r < 4; ++r) {
                    int gr = row0 + wm + 16 * mi + q * 4 + r;
                    if (gr < M) resout[(size_t)gr * 121 + gcl] = acc[mi][ni][r];
                }
            }
        }
        return;
    }

    // shared reduction buffers (reuse As): sred[256] escore sums, sredm[128] rowmax
    float* sred  = (float*)As;
    int*   sredm = (int*)(sred + 256);
    if (t < 256) sred[t] = 0.f;
    if (t < 128) sredm[t] = 0;
    __syncthreads();

    float av[4], dv[4];
#pragma unroll
    for (int ni = 0; ni < 4; ++ni) {
        int gc = col0 + wn + 16 * ni + l15;
        av[ni] = asv[gc];
        dv[ni] = adv[gc];
    }
#pragma unroll
    for (int mi = 0; mi < 4; ++mi) {
#pragma unroll
        for (int r = 0; r < 4; ++r) {
            float ps = 0.f, pd = 0.f, mx = 0.f;
#pragma unroll
            for (int ni = 0; ni < 4; ++ni) {
                ps = fmaf(acc[mi][ni][r], av[ni], ps);
                pd = fmaf(acc[mi][ni][r], dv[ni], pd);
                mx = fmaxf(mx, fabsf(acc[mi][ni][r]));
            }
#pragma unroll
            for (int off = 1; off < 16; off <<= 1) {
                ps += __shfl_xor(ps, off);
                pd += __shfl_xor(pd, off);
                mx = fmaxf(mx, __shfl_xor(mx, off));
            }
            if (l15 == 0) {
                int rloc = wm + 16 * mi + 4 * q + r;
                atomicAdd(&sred[rloc * 2 + 0], ps);
                atomicAdd(&sred[rloc * 2 + 1], pd);
                atomicMax(&sredm[rloc], __float_as_int(mx));
            }
        }
    }
    __syncthreads();

    // int8 store
#pragma unroll
    for (int mi = 0; mi < 4; ++mi) {
#pragma unroll
        for (int r = 0; r < 4; ++r) {
            int rloc = wm + 16 * mi + 4 * q + r;
            float rm = fmaxf(__int_as_float(sredm[rloc]), 1e-20f);
            float iq = 127.f / rm;
            int gr = row0 + rloc;
#pragma unroll
            for (int ni = 0; ni < 4; ++ni) {
                int gc = col0 + wn + 16 * ni + l15;
                if (gr < M)
                    Cq[(size_t)gr * NS + gc] = (signed char)(int)rintf(acc[mi][ni][r] * iq);
            }
        }
    }

    if (t < 128) {
        int gr = row0 + t;
        if (gr < M) {
            float2 ev;
            ev.x = sred[t * 2 + 0];
            ev.y = fmaxf(__int_as_float(sredm[t]), 1e-20f) * (1.f / 127.f);
            esq[(size_t)gr * Hl + bx] = ev;
            e_d[(size_t)gr * Hl + bx] = sred[t * 2 + 1];
        }
    }
}

// ---------------------------------------------------------------------------
// Layer-1 fused GEMM: x1 = elu(aggx_h @ W1_h + x0 @ R1_h), blockIdx.x = head.
// ---------------------------------------------------------------------------
__global__ __launch_bounds__(256) void gemm_l1(const unsigned short* __restrict__ aggx,
                                               const unsigned short* __restrict__ w1t,
                                               const unsigned short* __restrict__ x0b,
                                               const unsigned short* __restrict__ r1t,
                                               unsigned short* __restrict__ C, int M) {
    __shared__ __align__(16) unsigned short As[128 * 32];
    __shared__ __align__(16) unsigned short Bs[128 * 32];

    const int t    = threadIdx.x;
    const int wave = t >> 6, lane = t & 63;
    const int wm   = (wave >> 1) * 64, wn = (wave & 1) * 64;
    const int l15  = lane & 15, q = lane >> 4;
    const int row0 = blockIdx.y * 128;
    const int head = blockIdx.x;
    const int ccol = head * 128;

    floatx4 acc[4][4];
#pragma unroll
    for (int i = 0; i < 4; ++i)
#pragma unroll
        for (int j = 0; j < 4; ++j) acc[i][j] = (floatx4){0.f, 0.f, 0.f, 0.f};

    for (int ph = 0; ph < 2; ++ph) {
        const unsigned short* A  = ph ? x0b : (aggx + ccol);
        const int AS             = ph ? 128 : 512;
        const unsigned short* BT = (ph ? r1t : w1t) + (size_t)ccol * 128;

        for (int k0 = 0; k0 < 128; k0 += 32) {
#pragma unroll
            for (int p = 0; p < 2; ++p) {
                int idx = p * 256 + t;
                int r = idx >> 2, qq = idx & 3;
                int ar = row0 + r; ar = (ar < M) ? ar : (M - 1);
                unsigned short* ldsA = As + (p * 2048 + wave * 512);
                unsigned short* ldsB = Bs + (p * 2048 + wave * 512);
                gload_lds16(A  + (size_t)ar * AS + k0 + qq * 8, ldsA);
                gload_lds16(BT + (size_t)r * 128 + k0 + qq * 8, ldsB);
            }
            __syncthreads();

            short8 af[4], bfr[4];
#pragma unroll
            for (int mi = 0; mi < 4; ++mi) af[mi]  = *(const short8*)&As[(wm + 16 * mi + l15) * 32 + q * 8];
#pragma unroll
            for (int ni = 0; ni < 4; ++ni) bfr[ni] = *(const short8*)&Bs[(wn + 16 * ni + l15) * 32 + q * 8];
#pragma unroll
            for (int mi = 0; mi < 4; ++mi)
#pragma unroll
                for (int ni = 0; ni < 4; ++ni)
                    acc[mi][ni] = __builtin_amdgcn_mfma_f32_16x16x32_bf16(af[mi], bfr[ni], acc[mi][ni], 0, 0, 0);
            __syncthreads();
        }
    }

#pragma unroll
    for (int ni = 0; ni < 4; ++ni) {
        int gc = ccol + wn + 16 * ni + l15;
#pragma unroll
        for (int mi = 0; mi < 4; ++mi) {
#pragma unroll
            for (int r = 0; r < 4; ++r) {
                int gr = row0 + wm + 16 * mi + q * 4 + r;
                if (gr < M) {
                    float z = acc[mi][ni][r];
                    z = (z > 0.f) ? z : (__expf(z) - 1.f);   // elu
                    C[(size_t)gr * 512 + gc] = f2bf(z);
                }
            }
        }
    }
}

// ---------------------------------------------------------------------------
// escore over x (layer 1): e_s[n,h] = x[n] . ws[h], 128-dim, 4 heads.
// ---------------------------------------------------------------------------
__global__ __launch_bounds__(256) void escore_x(const unsigned short* __restrict__ x,
                                                const float* __restrict__ ws,
                                                const float* __restrict__ wd,
                                                float* __restrict__ e_s,
                                                float* __restrict__ e_d) {
    const int wave = threadIdx.x >> 6, lane = threadIdx.x & 63;
    const int n = blockIdx.x * 4 + wave;
    const int h = lane >> 4, seg = lane & 15;

    short8 hv = *(const short8*)(x + (size_t)n * 128 + seg * 8);
    float4 w0 = *(const float4*)(ws + h * 128 + seg * 8);
    float4 w1 = *(const float4*)(ws + h * 128 + seg * 8 + 4);
    float4 d0 = *(const float4*)(wd + h * 128 + seg * 8);
    float4 d1 = *(const float4*)(wd + h * 128 + seg * 8 + 4);
    float av[8] = {w0.x, w0.y, w0.z, w0.w, w1.x, w1.y, w1.z, w1.w};
    float dv[8] = {d0.x, d0.y, d0.z, d0.w, d1.x, d1.y, d1.z, d1.w};

    float ps = 0.f, pd = 0.f;
#pragma unroll
    for (int j = 0; j < 8; ++j) {
        float xv = bf2f((unsigned short)hv[j]);
        ps = fmaf(xv, av[j], ps);
        pd = fmaf(xv, dv[j], pd);
    }
#pragma unroll
    for (int off = 1; off < 16; off <<= 1) {
        ps += __shfl_xor(ps, off);
        pd += __shfl_xor(pd, off);
    }
    if (seg == 0) {
        e_s[(size_t)n * 4 + h] = ps;
        e_d[(size_t)n * 4 + h] = pd;
    }
}

// ---------------------------------------------------------------------------
// Layer-1 x-aggregation: aggx[n,h,u] = (1/den_h) sum_e pw[e,h] x[src_e, u].
// ---------------------------------------------------------------------------
__global__ __launch_bounds__(256) void agg_x512(const unsigned short* __restrict__ x,
                                                const float* __restrict__ pw,
                                                const int* __restrict__ rowp,
                                                const int* __restrict__ esrc,
                                                unsigned short* __restrict__ aggx) {
    const int wave = threadIdx.x >> 6, lane = threadIdx.x & 63;
    const int n = blockIdx.x * 4 + wave;
    const int lid = lane & 31, half = lane >> 5;
    const int beg = rowp[n], end = rowp[n + 1];

    float den[4] = {0.f, 0.f, 0.f, 0.f};
    float acc[4][4];
#pragma unroll
    for (int h = 0; h < 4; ++h)
#pragma unroll
        for (int j = 0; j < 4; ++j) acc[h][j] = 0.f;

    int e = beg;
    for (; e + 8 <= end; e += 8) {
        int s[4];
        float4 p[4];
        short4v xr[4];
#pragma unroll
        for (int k = 0; k < 4; ++k) s[k] = esrc[e + 2 * k + half];
#pragma unroll
        for (int k = 0; k < 4; ++k) p[k] = *(const float4*)(pw + (size_t)(e + 2 * k + half) * 4);
#pragma unroll
        for (int k = 0; k < 4; ++k) xr[k] = *(const short4v*)(x + (size_t)s[k] * 128 + lid * 4);
#pragma unroll
        for (int k = 0; k < 4; ++k) {
            den[0] += p[k].x; den[1] += p[k].y; den[2] += p[k].z; den[3] += p[k].w;
#pragma unroll
            for (int j = 0; j < 4; ++j) {
                float xf = bf2f((unsigned short)xr[k][j]);
                acc[0][j] = fmaf(p[k].x, xf, acc[0][j]);
                acc[1][j] = fmaf(p[k].y, xf, acc[1][j]);
                acc[2][j] = fmaf(p[k].z, xf, acc[2][j]);
                acc[3][j] = fmaf(p[k].w, xf, acc[3][j]);
            }
        }
    }
    for (; e < end; e += 2) {
        int idx = e + half;
        if (idx < end) {
            int s = esrc[idx];
            float4 p = *(const float4*)(pw + (size_t)idx * 4);
            short4v xr = *(const short4v*)(x + (size_t)s * 128 + lid * 4);
            den[0] += p.x; den[1] += p.y; den[2] += p.z; den[3] += p.w;
#pragma unroll
            for (int j = 0; j < 4; ++j) {
                float xf = bf2f((unsigned short)xr[j]);
                acc[0][j] = fmaf(p.x, xf, acc[0][j]);
                acc[1][j] = fmaf(p.y, xf, acc[1][j]);
                acc[2][j] = fmaf(p.z, xf, acc[2][j]);
                acc[3][j] = fmaf(p.w, xf, acc[3][j]);
            }
        }
    }

    // combine half-waves
#pragma unroll
    for (int h = 0; h < 4; ++h) {
        den[h] += __shfl_xor(den[h], 32);
#pragma unroll
        for (int j = 0; j < 4; ++j) acc[h][j] += __shfl_xor(acc[h][j], 32);
    }
    if (half == 0) {
#pragma unroll
        for (int h = 0; h < 4; ++h) {
            const float inv = 1.f / fmaxf(den[h], 1e-9f);
            ushort4 o;
            o.x = f2bf(acc[h][0] * inv);
            o.y = f2bf(acc[h][1] * inv);
            o.z = f2bf(acc[h][2] * inv);
            o.w = f2bf(acc[h][3] * inv);
            *(ushort4*)(aggx + (size_t)n * 512 + h * 128 + lid * 4) = o;
        }
    }
}

// ---------------------------------------------------------------------------
// Wave-per-node aggregation, layer 2, int8 hbuf stride 512 + packed
// esq {e_s, scl} float2. den uses unscaled p; acc uses p*scl. 8-edge pipeline.
// ---------------------------------------------------------------------------
__global__ __launch_bounds__(256) void agg_q512(const signed char* __restrict__ hq,
                                                const float2* __restrict__ esq,
                                                const float* __restrict__ ed,
                                                const int* __restrict__ rowp,
                                                const int* __restrict__ esrc,
                                                const unsigned short* res,
                                                unsigned short* out) {
    const int wave = threadIdx.x >> 6, lane = threadIdx.x & 63;
    const int n = blockIdx.x * 4 + wave;      // grid*4 == NN exactly
    const int h = lane >> 4;
    const int beg = rowp[n], end = rowp[n + 1];
    const float edh = ed[(size_t)n * 4 + h];

    float den = 0.f;
    float acc[8];
#pragma unroll
    for (int j = 0; j < 8; ++j) acc[j] = 0.f;

    int e = beg;
    for (; e + 8 <= end; e += 8) {
        int s[8];
#pragma unroll
        for (int k = 0; k < 8; ++k) s[k] = esrc[e + k];
        schar8 r[8];
#pragma unroll
        for (int k = 0; k < 8; ++k) r[k] = *(const schar8*)(hq + (size_t)s[k] * 512 + lane * 8);
        float p[8], qv[8];
#pragma unroll
        for (int k = 0; k < 8; ++k) {
            float2 ev = esq[(size_t)s[k] * 4 + h];
            float pv = __expf(leaky(ev.x + edh));
            p[k] = pv;
            qv[k] = pv * ev.y;
        }
#pragma unroll
        for (int k = 0; k < 8; ++k) den += p[k];
#pragma unroll
        for (int j = 0; j < 8; ++j) {
            float a = acc[j];
#pragma unroll
            for (int k = 0; k < 8; ++k) a = fmaf(qv[k], (float)r[k][j], a);
            acc[j] = a;
        }
    }
    for (; e < end; ++e) {
        int s0 = esrc[e];
        schar8 r0 = *(const schar8*)(hq + (size_t)s0 * 512 + lane * 8);
        float2 ev = esq[(size_t)s0 * 4 + h];
        float p0 = __expf(leaky(ev.x + edh));
        float q0 = p0 * ev.y;
        den += p0;
#pragma unroll
        for (int j = 0; j < 8; ++j) acc[j] = fmaf(q0, (float)r0[j], acc[j]);
    }

    const float inv = 1.f / fmaxf(den, 1e-9f);
    short8 rv = *(const short8*)(res + (size_t)n * 512 + lane * 8);
    short8 ov;
#pragma unroll
    for (int j = 0; j < 8; ++j) {
        float z = acc[j] * inv + bf2f((unsigned short)rv[j]);
        z = (z > 0.f) ? z : (__expf(z) - 1.f);   // elu
        ov[j] = (short)f2bf(z);
    }
    *(short8*)(out + (size_t)n * 512 + lane * 8) = ov;
}

// ---------------------------------------------------------------------------
// Wave-per-node aggregation, layer 3, int8 stride 768, packed esq.
// r12 structure REVERTED (best measured: 123.9 us): chunk0 all 64 lanes;
// chunk1 exec-masked on lanes<32 (h1 = 4+(lane>>4), elem 512+lane*8).
// r13/r14 balanced-chunk1 variants measured 177/138 us -> abandoned.
// ---------------------------------------------------------------------------
__global__ __launch_bounds__(256) void agg_q768(const signed char* __restrict__ hq,
                                                const float2* __restrict__ esq,
                                                const float* __restrict__ ed,
                                                const int* __restrict__ rowp,
                                                const int* __restrict__ esrc,
                                                const float* res,
                                                float* out) {
    __shared__ float s_vals[4][768];
    const int wave = threadIdx.x >> 6, lane = threadIdx.x & 63;
    const int n = blockIdx.x * 4 + wave;
    const int beg = rowp[n], end = rowp[n + 1];

    const int h0 = lane >> 4;          // chunk0 head
    const bool has1 = (lane < 32);
    const int h1 = 4 + (lane >> 4);    // chunk1 head (valid when has1)
    const float edh0 = ed[(size_t)n * 6 + h0];
    const float edh1 = has1 ? ed[(size_t)n * 6 + h1] : 0.f;

    float den0 = 0.f, den1 = 0.f;
    float acc0[8], acc1[8];
#pragma unroll
    for (int j = 0; j < 8; ++j) { acc0[j] = 0.f; acc1[j] = 0.f; }

    int e = beg;
    for (; e + 4 <= end; e += 4) {
        int s[4];
#pragma unroll
        for (int k = 0; k < 4; ++k) s[k] = esrc[e + k];
        schar8 r0[4];
#pragma unroll
        for (int k = 0; k < 4; ++k) r0[k] = *(const schar8*)(hq + (size_t)s[k] * 768 + lane * 8);
        float p0[4], q0[4];
#pragma unroll
        for (int k = 0; k < 4; ++k) {
            float2 ev = esq[(size_t)s[k] * 6 + h0];
            float pv = __expf(leaky(ev.x + edh0));
            p0[k] = pv;
            q0[k] = pv * ev.y;
        }
        den0 += (p0[0] + p0[1]) + (p0[2] + p0[3]);
#pragma unroll
        for (int j = 0; j < 8; ++j)
            acc0[j] = fmaf(q0[0], (float)r0[0][j],
                      fmaf(q0[1], (float)r0[1][j],
                      fmaf(q0[2], (float)r0[2][j],
                      fmaf(q0[3], (float)r0[3][j], acc0[j]))));
        if (has1) {
            schar8 r1[4];
#pragma unroll
            for (int k = 0; k < 4; ++k) r1[k] = *(const schar8*)(hq + (size_t)s[k] * 768 + 512 + lane * 8);
            float p1[4], q1[4];
#pragma unroll
            for (int k = 0; k < 4; ++k) {
                float2 ev = esq[(size_t)s[k] * 6 + h1];
                float pv = __expf(leaky(ev.x + edh1));
                p1[k] = pv;
                q1[k] = pv * ev.y;
            }
            den1 += (p1[0] + p1[1]) + (p1[2] + p1[3]);
#pragma unroll
            for (int j = 0; j < 8; ++j)
                acc1[j] = fmaf(q1[0], (float)r1[0][j],
                          fmaf(q1[1], (float)r1[1][j],
                          fmaf(q1[2], (float)r1[2][j],
                          fmaf(q1[3], (float)r1[3][j], acc1[j]))));
        }
    }
    for (; e < end; ++e) {
        int s = esrc[e];
        schar8 r0 = *(const schar8*)(hq + (size_t)s * 768 + lane * 8);
        float2 ev0 = esq[(size_t)s * 6 + h0];
        float p0 = __expf(leaky(ev0.x + edh0));
        float q0 = p0 * ev0.y;
        den0 += p0;
#pragma unroll
        for (int j = 0; j < 8; ++j) acc0[j] = fmaf(q0, (float)r0[j], acc0[j]);
        if (has1) {
            schar8 r1 = *(const schar8*)(hq + (size_t)s * 768 + 512 + lane * 8);
            float2 ev1 = esq[(size_t)s * 6 + h1];
            float p1 = __expf(leaky(ev1.x + edh1));
            float q1 = p1 * ev1.y;
            den1 += p1;
#pragma unroll
            for (int j = 0; j < 8; ++j) acc1[j] = fmaf(q1, (float)r1[j], acc1[j]);
        }
    }

    const float inv0 = 1.f / fmaxf(den0, 1e-9f);
#pragma unroll
    for (int j = 0; j < 8; ++j) s_vals[wave][lane * 8 + j] = acc0[j] * inv0;
    if (has1) {
        const float inv1 = 1.f / fmaxf(den1, 1e-9f);
#pragma unroll
        for (int j = 0; j < 8; ++j) s_vals[wave][512 + lane * 8 + j] = acc1[j] * inv1;
    }
    __syncthreads();

    for (int u = lane; u < 121; u += 64) {
        float sum = 0.f;
#pragma unroll
        for (int hh = 0; hh < 6; ++hh) sum += s_vals[wave][hh * 128 + u];
        float v = sum * (1.f / 6.f) + res[(size_t)n * 121 + u];
        __builtin_nontemporal_store(v, out + (size_t)n * 121 + u);
    }
}

// ---------------------------------------------------------------------------
// Launch
// ---------------------------------------------------------------------------
static inline size_t align256(size_t x) { return (x + 255) & ~(size_t)255; }

extern "C" void kernel_launch(void* const* d_in, const int* in_sizes, int n_in,
                              void* d_out, int out_size, void* d_ws, size_t ws_size,
                              hipStream_t stream) {
    const float* x0  = (const float*)d_in[0];   // [50000,128] fp32
    const int* edges = (const int*)d_in[1];     // [800000,2] int32
    const float* W1  = (const float*)d_in[2];   // [128,512]
    const float* a1s = (const float*)d_in[3];
    const float* a1d = (const float*)d_in[4];
    const float* R1  = (const float*)d_in[5];   // [128,512]
    const float* W2  = (const float*)d_in[6];   // [512,512]
    const float* a2s = (const float*)d_in[7];
    const float* a2d = (const float*)d_in[8];
    const float* W3  = (const float*)d_in[9];   // [512,726]
    const float* a3s = (const float*)d_in[10];
    const float* a3d = (const float*)d_in[11];
    const float* R3  = (const float*)d_in[12];  // [512,121]
    float* out = (float*)d_out;                 // [50000,121] fp32

    // workspace carve (~160 MB). w3t/r3t MUST stay contiguous (gemm_esc R3 head).
    char* w = (char*)d_ws;
    size_t off = 0;
    unsigned short* hbuf = (unsigned short*)(w + off); off = align256(off + (size_t)NN * 768 * 2);
    unsigned short* x1   = (unsigned short*)(w + off); off = align256(off + (size_t)NN * 512 * 2);
    float* es  = (float*)(w + off); off = align256(off + (size_t)NN * 6 * 4);
    float* ed  = (float*)(w + off); off = align256(off + (size_t)NN * 6 * 4);
    int* rowp  = (int*)(w + off);   off = align256(off + (size_t)(NN + 1) * 4);
    int* esrc  = (int*)(w + off);   off = align256(off + (size_t)NE * 4);
    int* edst  = (int*)(w + off);   off = align256(off + (size_t)NE * 4);
    float* pw  = (float*)(w + off); off = align256(off + (size_t)NE * 4 * 4 + 256);
    unsigned short* w1t = (unsigned short*)(w + off); off = align256(off + (size_t)512 * 128 * 2);
    unsigned short* r1t = (unsigned short*)(w + off); off = align256(off + (size_t)512 * 128 * 2);
    unsigned short* w2t = (unsigned short*)(w + off); off = align256(off + (size_t)512 * 512 * 2);
    unsigned short* w3t = (unsigned short*)(w + off); off = align256(off + (size_t)768 * 512 * 2);
    unsigned short* r3t = (unsigned short*)(w + off); off = align256(off + (size_t)128 * 512 * 2);
    float* wsb = (float*)(w + off); off = align256(off + (size_t)512 * 4);
    float* wdb = (float*)(w + off); off = align256(off + (size_t)512 * 4);
    float* a3sp = (float*)(w + off); off = align256(off + (size_t)768 * 4);
    float* a3dp = (float*)(w + off); off = align256(off + (size_t)768 * 4);
    float2* esq = (float2*)(w + off); off = align256(off + (size_t)NN * 6 * 8);
    int* deg = (int*)es;                     // overlay: dead after CSR build
    int* cur = (int*)ed;
    // layer-1 overlays inside hbuf (hbuf not used until layer-2 GEMM writes it):
    unsigned short* x0b  = hbuf;                          // [NN,128] bf16 = 12.8 MB
    unsigned short* aggx = hbuf + (size_t)NN * 128;       // [NN,512] bf16 = 51.2 MB
    signed char* hq = (signed char*)hbuf;                 // int8 views (L2: 25.6 MB, L3: 38.4 MB)
    (void)ws_size;

    const int EB = (NE + 255) / 256;
    const int MB = MBLK;               // 391
    const int AB = NN / 4;             // 12500 blocks, 4 waves each

    // --- prep (weights + deg zero + x0 conversion, one dispatch) ---
    prep2<<<9782, 256, 0, stream>>>(W1, R1, W2, W3, R3, a1s, a1d, a3s, a3d, x0,
                                    w1t, r1t, w2t, w3t, r3t, wsb, wdb, a3sp, a3dp,
                                    deg, x0b);

    // --- CSR build ---
    deg_kernel<<<EB, 256, 0, stream>>>(edges, deg, NE);
    scan_kernel<<<1, 256, 0, stream>>>(deg, rowp, cur, NN);
    scatter_kernel<<<EB, 256, 0, stream>>>(edges, cur, esrc, edst, NE);

    // --- Layer 1 (x-aggregation + fused dual-K GEMM) ---
    escore_x<<<AB, 256, 0, stream>>>(x0b, wsb, wdb, es, ed);
    pw_kernel<4><<<EB, 256, 0, stream>>>(es, ed, esrc, edst, pw, NE);
    agg_x512<<<AB, 256, 0, stream>>>(x0b, pw, rowp, esrc, aggx);
    gemm_l1<<<dim3(4, MB), 256, 0, stream>>>(aggx, w1t, x0b, r1t, x1, NN);

    // --- Layer 2: GEMM + escore + int8 quant (XCD-grouped grid 8*49*4=1568) ---
    gemm_esc<<<8 * 49 * 4, 256, 0, stream>>>(x1, w2t, hq, esq, ed,
                                             a2s, a2d, out, NN, 512, 4, 4);
    agg_q512<<<AB, 256, 0, stream>>>(hq, esq, ed, rowp, esrc, x1, x1);

    // --- Layer 3: GEMM + escore + int8 quant + R3 head (grid 8*49*7=2744) ---
    gemm_esc<<<8 * 49 * 7, 256, 0, stream>>>(x1, w3t, hq, esq, ed,
                                             a3sp, a3dp, out, NN, 768, 6, 7);
    agg_q768<<<AB, 256, 0, stream>>>(hq, esq, ed, rowp, esrc, out, out);
}